// Round 11
// baseline (315.539 us; speedup 1.0000x reference)
//
#include <hip/hip_runtime.h>
#include <hip/hip_bf16.h>
#include <math.h>

typedef __hip_bfloat16 bf16;
typedef short bf16x8 __attribute__((ext_vector_type(8)));
typedef short bf16x4 __attribute__((ext_vector_type(4)));
typedef float f32x4 __attribute__((ext_vector_type(4)));

#define NB 8
#define LQ 3072
#define CC 768
#define NHEADS 6
#define NPTS 4
#define DHEAD 128
#define HLVL 64
#define WLVL 64
#define LIN 4096
#define HID 192
#define BLTOT 24576   // NB*LQ
#define FROWS 32768   // NB*LIN

__device__ __forceinline__ float bf2f(short u)
{ return __uint_as_float(((unsigned)(unsigned short)u) << 16); }

template<int N_>
__device__ __forceinline__ void wait_vmcnt()
{
    if constexpr (N_ == 0)      asm volatile("s_waitcnt vmcnt(0)" ::: "memory");
    else if constexpr (N_ == 2) asm volatile("s_waitcnt vmcnt(2)" ::: "memory");
    else if constexpr (N_ == 4) asm volatile("s_waitcnt vmcnt(4)" ::: "memory");
    else if constexpr (N_ == 5) asm volatile("s_waitcnt vmcnt(5)" ::: "memory");
    else if constexpr (N_ == 6) asm volatile("s_waitcnt vmcnt(6)" ::: "memory");
    else if constexpr (N_ == 8) asm volatile("s_waitcnt vmcnt(8)" ::: "memory");
    else static_assert(N_ == 0, "add a vmcnt case");
}

// ---------------- merged prep: 4 weight transposes + dots weight + LN(feat), one launch ----------
__device__ __forceinline__ void wt_tile(float (*t)[65], const float* __restrict__ src,
                                        bf16* __restrict__ dst, int K, int N, int tn0, int tk0)
{
    const int r = threadIdx.x >> 6, c = threadIdx.x & 63;
    #pragma unroll
    for (int i = 0; i < 16; ++i)
        t[i * 4 + r][c] = src[(size_t)(tk0 + i * 4 + r) * N + tn0 + c];
    __syncthreads();
    #pragma unroll
    for (int i = 0; i < 16; ++i)
        dst[(size_t)(tn0 + i * 4 + r) * K + tk0 + c] = __float2bfloat16(t[c][i * 4 + r]);
}

__global__ __launch_bounds__(256)
void prep_kernel(const float* __restrict__ vp_w, const float* __restrict__ op_w,
                 const float* __restrict__ fc1_w, const float* __restrict__ fc2_w,
                 const float* __restrict__ so_w, const float* __restrict__ so_b,
                 const float* __restrict__ aw_w, const float* __restrict__ aw_b,
                 const float* __restrict__ feat, const float* __restrict__ fn_w,
                 const float* __restrict__ fn_b,
                 bf16* __restrict__ vp_wt, bf16* __restrict__ op_wt,
                 bf16* __restrict__ fc1_wt, bf16* __restrict__ fc2_wt,
                 bf16* __restrict__ dots_wt, float* __restrict__ db,
                 bf16* __restrict__ f_ln)
{
    __shared__ float t[64][65];
    int b = blockIdx.x;
    if (b < 144)      wt_tile(t, vp_w, vp_wt, 768, 768, (b % 12) * 64, (b / 12) * 64);
    else if (b < 288) { b -= 144; wt_tile(t, op_w, op_wt, 768, 768, (b % 12) * 64, (b / 12) * 64); }
    else if (b < 324) { b -= 288; wt_tile(t, fc1_w, fc1_wt, 768, 192, (b % 3) * 64, (b / 3) * 64); }
    else if (b < 360) { b -= 324; wt_tile(t, fc2_w, fc2_wt, 192, 768, (b % 12) * 64, (b / 12) * 64); }
    else if (b < 744) {
        b -= 360;
        int i = b * 256 + threadIdx.x;          // over 128*768
        if (i < 128 * 768) {
            int n = i / 768, k = i - n * 768;
            float v = 0.f;
            if (n < 48) v = so_w[(size_t)k * 48 + n];
            else if (n < 72) v = aw_w[(size_t)k * 24 + (n - 48)];
            dots_wt[i] = __float2bfloat16(v);
        }
        if (i < 128) {
            float bv = 0.f;
            if (i < 48) bv = so_b[i];
            else if (i < 72) bv = aw_b[i - 48];
            db[i] = bv;
        }
    } else {
        // LN(feat) -> f_ln, wave per row
        const int row = (b - 744) * 4 + (threadIdx.x >> 6);
        const int lane = threadIdx.x & 63;
        const f32x4* xr = (const f32x4*)(feat + (size_t)row * CC);
        f32x4 f0 = xr[lane], f1 = xr[64 + lane], f2 = xr[128 + lane];
        float s = 0.f, ss = 0.f;
        #pragma unroll
        for (int k = 0; k < 4; ++k) {
            s += f0[k] + f1[k] + f2[k];
            ss += f0[k] * f0[k] + f1[k] * f1[k] + f2[k] * f2[k];
        }
        #pragma unroll
        for (int o = 32; o > 0; o >>= 1) { s += __shfl_down(s, o); ss += __shfl_down(ss, o); }
        s = __shfl(s, 0); ss = __shfl(ss, 0);
        const float m = s * (1.f / CC);
        const float rs = rsqrtf(ss * (1.f / CC) - m * m + 1e-6f);
        const f32x4* w4 = (const f32x4*)fn_w;
        const f32x4* b4 = (const f32x4*)fn_b;
        bf16* orow = f_ln + (size_t)row * CC;
        #pragma unroll
        for (int j = 0; j < 3; ++j) {
            f32x4 fj = (j == 0) ? f0 : (j == 1) ? f1 : f2;
            f32x4 wj = w4[j * 64 + lane], bj = b4[j * 64 + lane];
            bf16 t4[4];
            #pragma unroll
            for (int k = 0; k < 4; ++k) t4[k] = __float2bfloat16((fj[k] - m) * rs * wj[k] + bj[k]);
            *(bf16x4*)(orow + j * 256 + lane * 4) = *(bf16x4*)t4;
        }
    }
}

// ---------------- bf16 MFMA GEMM (256 thr): 2-deep pipelined, XOR-swizzled LDS ----------------
// MODE 0: bf16 out = acc+bias
// MODE 3: bf16 out = acc+bias+res_f32   (res prefetched to regs)
// MODE 4: f32  out = acc+bias+res_bf16  (res prefetched to regs)
template<int BM, int BN, int WM, int WN, int MODE>
__global__ __launch_bounds__(256)
void gemm_kernel(const bf16* __restrict__ A, const bf16* __restrict__ Bt,
                 const float* __restrict__ bias, const void* __restrict__ resv,
                 void* __restrict__ outv, int M, int N, int K)
{
    constexpr int WAVES_N = BN / WN;
    constexpr int FM = WM / 16, FN = WN / 16;
    constexpr int CWA = BM / 32;
    constexpr int CWB = BN / 32;
    constexpr int LPT = CWA + CWB;
    constexpr int ABYTES = BM * 256;
    constexpr int DBUF_BYTES = (BM + BN) * 256;
    constexpr int EPI_BYTES = BM * BN * 4;
    constexpr size_t SMEM_BYTES = DBUF_BYTES > EPI_BYTES ? DBUF_BYTES : EPI_BYTES;
    __shared__ __align__(16) char smem[SMEM_BYTES];
    bf16* sA = (bf16*)smem;
    bf16* sB = (bf16*)(smem + ABYTES);
    float* epi = (float*)smem;

    const int tid = threadIdx.x;
    const int lane = tid & 63;
    const int wave = tid >> 6;

    const int nwgx = gridDim.x;
    const int nwg = nwgx * gridDim.y;
    const int bid = blockIdx.y * nwgx + blockIdx.x;
    const int swz = (bid & 7) * (nwg >> 3) + (bid >> 3);
    const int m0 = (swz / nwgx) * BM;
    const int n0 = (swz % nwgx) * BN;

    const int wm = (wave / WAVES_N) * WM;
    const int wn = (wave % WAVES_N) * WN;

    const int srow = lane >> 3;
    const int scol = ((lane & 7) ^ srow) * 8;

    constexpr int GPR8 = BN / 8;
    constexpr int GPT8 = (BM * BN / 8) / 256;
    constexpr int QPR4 = BN / 4;
    constexpr int QPT4 = (BM * BN / 4) / 256;
    float4 pr0[GPT8], pr1[GPT8];
    bf16x4 prb[QPT4];
    if constexpr (MODE == 3) {
        const float* resf = (const float*)resv;
        #pragma unroll
        for (int k = 0; k < GPT8; ++k) {
            const int f = k * 256 + tid;
            const int rr = f / GPR8, cc = (f % GPR8) * 8;
            const size_t gidx = (size_t)(m0 + rr) * N + n0 + cc;
            pr0[k] = *(const float4*)&resf[gidx];
            pr1[k] = *(const float4*)&resf[gidx + 4];
        }
    }
    if constexpr (MODE == 4) {
        const bf16* resb = (const bf16*)resv;
        #pragma unroll
        for (int k = 0; k < QPT4; ++k) {
            const int f = k * 256 + tid;
            const int rr = f / QPR4, cc = (f % QPR4) * 4;
            prb[k] = *(const bf16x4*)&resb[(size_t)(m0 + rr) * N + n0 + cc];
        }
    }

#define STAGE(tt, half)                                                                            \
    { const int k0_ = (tt) * 64;                                                                   \
      _Pragma("unroll")                                                                            \
      for (int i_ = 0; i_ < CWA; ++i_) {                                                           \
        const int c_ = i_ * 4 + wave;                                                              \
        __builtin_amdgcn_global_load_lds(                                                          \
          (const __attribute__((address_space(1))) void*)(A + (size_t)(m0 + c_ * 8 + srow) * K + k0_ + scol), \
          (__attribute__((address_space(3))) void*)(sA + (half) * (BM * 64) + c_ * 512), 16, 0, 0); } \
      _Pragma("unroll")                                                                            \
      for (int i_ = 0; i_ < CWB; ++i_) {                                                           \
        const int c_ = i_ * 4 + wave;                                                              \
        __builtin_amdgcn_global_load_lds(                                                          \
          (const __attribute__((address_space(1))) void*)(Bt + (size_t)(n0 + c_ * 8 + srow) * K + k0_ + scol), \
          (__attribute__((address_space(3))) void*)(sB + (half) * (BN * 64) + c_ * 512), 16, 0, 0); } }

    f32x4 acc[FM][FN] = {};
    const int nt = K >> 6;

    STAGE(0, 0);
    STAGE(1, 1);

    for (int t = 0; t < nt; ++t) {
        const int half = t & 1;
        if (t + 1 < nt) wait_vmcnt<LPT>();
        else            wait_vmcnt<0>();
        __builtin_amdgcn_s_barrier();
        const bf16* cA = sA + half * (BM * 64);
        const bf16* cB = sB + half * (BN * 64);
        #pragma unroll
        for (int kki = 0; kki < 2; ++kki) {
            const int kslot = kki * 4 + (lane >> 4);
            bf16x8 aF[FM], bF[FN];
            #pragma unroll
            for (int i = 0; i < FM; ++i) {
                const int row = wm + i * 16 + (lane & 15);
                aF[i] = *(const bf16x8*)(&cA[row * 64 + ((kslot ^ (row & 7)) * 8)]);
            }
            #pragma unroll
            for (int j = 0; j < FN; ++j) {
                const int row = wn + j * 16 + (lane & 15);
                bF[j] = *(const bf16x8*)(&cB[row * 64 + ((kslot ^ (row & 7)) * 8)]);
            }
            #pragma unroll
            for (int i = 0; i < FM; ++i) {
                #pragma unroll
                for (int j = 0; j < FN; ++j)
                    acc[i][j] = __builtin_amdgcn_mfma_f32_16x16x32_bf16(aF[i], bF[j], acc[i][j], 0, 0, 0);
            }
        }
        asm volatile("s_waitcnt lgkmcnt(0)" ::: "memory");
        __builtin_amdgcn_s_barrier();
        if (t + 2 < nt) STAGE(t + 2, half);
    }
#undef STAGE

    #pragma unroll
    for (int j = 0; j < FN; ++j) {
        const int colL = wn + j * 16 + (lane & 15);
        const float bj = bias[n0 + colL];
        #pragma unroll
        for (int i = 0; i < FM; ++i) {
            #pragma unroll
            for (int r = 0; r < 4; ++r) {
                const int rowL = wm + i * 16 + ((lane >> 4) << 2) + r;
                const int addr = rowL * BN + ((((colL >> 2) ^ (rowL & 7)) << 2) | (colL & 3));
                epi[addr] = acc[i][j][r] + bj;
            }
        }
    }
    __syncthreads();

    if constexpr (MODE == 0 || MODE == 3) {
        #pragma unroll
        for (int k = 0; k < GPT8; ++k) {
            const int f = k * 256 + tid;
            const int rr = f / GPR8, cc = (f % GPR8) * 8;
            const int g0 = ((cc >> 2) ^ (rr & 7)) << 2;
            const int g1 = (((cc >> 2) + 1) ^ (rr & 7)) << 2;
            float4 v0 = *(const float4*)&epi[rr * BN + g0];
            float4 v1 = *(const float4*)&epi[rr * BN + g1];
            if constexpr (MODE == 3) {
                v0.x += pr0[k].x; v0.y += pr0[k].y; v0.z += pr0[k].z; v0.w += pr0[k].w;
                v1.x += pr1[k].x; v1.y += pr1[k].y; v1.z += pr1[k].z; v1.w += pr1[k].w;
            }
            bf16 tmp[8];
            tmp[0] = __float2bfloat16(v0.x); tmp[1] = __float2bfloat16(v0.y);
            tmp[2] = __float2bfloat16(v0.z); tmp[3] = __float2bfloat16(v0.w);
            tmp[4] = __float2bfloat16(v1.x); tmp[5] = __float2bfloat16(v1.y);
            tmp[6] = __float2bfloat16(v1.z); tmp[7] = __float2bfloat16(v1.w);
            *(bf16x8*)((bf16*)outv + (size_t)(m0 + rr) * N + n0 + cc) = *(bf16x8*)tmp;
        }
    } else {
        #pragma unroll
        for (int k = 0; k < QPT4; ++k) {
            const int f = k * 256 + tid;
            const int rr = f / QPR4, cc = (f % QPR4) * 4;
            const int gs = ((cc >> 2) ^ (rr & 7)) << 2;
            float4 v = *(const float4*)&epi[rr * BN + gs];
            if constexpr (MODE == 4) {
                v.x += bf2f(prb[k][0]); v.y += bf2f(prb[k][1]);
                v.z += bf2f(prb[k][2]); v.w += bf2f(prb[k][3]);
            }
            *(float4*)&((float*)outv)[(size_t)(m0 + rr) * N + n0 + cc] = v;
        }
    }
}

// ---------------- value GEMM: 512 threads, 128x128 tile (64KB LDS -> 2 blocks/CU) ----------------
__global__ __launch_bounds__(512)
void gemm_value_kernel(const bf16* __restrict__ A, const bf16* __restrict__ Bt,
                       const float* __restrict__ bias, bf16* __restrict__ outb,
                       int M, int N, int K)
{
    constexpr int BM = 128, BN = 128;
    constexpr int FM = 2, FN = 4;               // wave tile 32x64; 8 waves = 4x2
    constexpr int LPT = 4;                      // 2 A + 2 B chunks per wave per tile
    __shared__ __align__(16) char smem[2 * (BM + BN) * 128];   // 64KB
    bf16* sA = (bf16*)smem;
    bf16* sB = (bf16*)(smem + 2 * BM * 128);
    float* epi = (float*)smem;                  // 64KB epilogue reuse

    const int tid = threadIdx.x;
    const int lane = tid & 63;
    const int wave = tid >> 6;

    const int nwgx = gridDim.x;
    const int nwg = nwgx * gridDim.y;
    const int bid = blockIdx.y * nwgx + blockIdx.x;
    const int swz = (bid & 7) * (nwg >> 3) + (bid >> 3);
    const int m0 = (swz / nwgx) * BM;
    const int n0 = (swz % nwgx) * BN;

    const int wm = (wave >> 1) * 32;
    const int wn = (wave & 1) * 64;
    const int srow = lane >> 3;
    const int scol = ((lane & 7) ^ srow) * 8;

#define STAGEV(tt, half)                                                                           \
    { const int k0_ = (tt) * 64;                                                                   \
      _Pragma("unroll")                                                                            \
      for (int i_ = 0; i_ < 2; ++i_) {                                                             \
        const int c_ = i_ * 8 + wave;                                                              \
        __builtin_amdgcn_global_load_lds(                                                          \
          (const __attribute__((address_space(1))) void*)(A + (size_t)(m0 + c_ * 8 + srow) * K + k0_ + scol), \
          (__attribute__((address_space(3))) void*)(sA + (half) * (BM * 64) + c_ * 512), 16, 0, 0); } \
      _Pragma("unroll")                                                                            \
      for (int i_ = 0; i_ < 2; ++i_) {                                                             \
        const int c_ = i_ * 8 + wave;                                                              \
        __builtin_amdgcn_global_load_lds(                                                          \
          (const __attribute__((address_space(1))) void*)(Bt + (size_t)(n0 + c_ * 8 + srow) * K + k0_ + scol), \
          (__attribute__((address_space(3))) void*)(sB + (half) * (BN * 64) + c_ * 512), 16, 0, 0); } }

    f32x4 acc[FM][FN] = {};
    const int nt = K >> 6;

    STAGEV(0, 0);
    STAGEV(1, 1);

    for (int t = 0; t < nt; ++t) {
        const int half = t & 1;
        if (t + 1 < nt) wait_vmcnt<LPT>();
        else            wait_vmcnt<0>();
        __builtin_amdgcn_s_barrier();
        const bf16* cA = sA + half * (BM * 64);
        const bf16* cB = sB + half * (BN * 64);
        #pragma unroll
        for (int kki = 0; kki < 2; ++kki) {
            const int kslot = kki * 4 + (lane >> 4);
            bf16x8 aF[FM], bF[FN];
            #pragma unroll
            for (int i = 0; i < FM; ++i) {
                const int row = wm + i * 16 + (lane & 15);
                aF[i] = *(const bf16x8*)(&cA[row * 64 + ((kslot ^ (row & 7)) * 8)]);
            }
            #pragma unroll
            for (int j = 0; j < FN; ++j) {
                const int row = wn + j * 16 + (lane & 15);
                bF[j] = *(const bf16x8*)(&cB[row * 64 + ((kslot ^ (row & 7)) * 8)]);
            }
            #pragma unroll
            for (int i = 0; i < FM; ++i) {
                #pragma unroll
                for (int j = 0; j < FN; ++j)
                    acc[i][j] = __builtin_amdgcn_mfma_f32_16x16x32_bf16(aF[i], bF[j], acc[i][j], 0, 0, 0);
            }
        }
        asm volatile("s_waitcnt lgkmcnt(0)" ::: "memory");
        __builtin_amdgcn_s_barrier();
        if (t + 2 < nt) STAGEV(t + 2, half);
    }
#undef STAGEV

    // ---- epilogue: acc -> LDS (swizzled) -> bf16x8 stores, 512 threads ----
    #pragma unroll
    for (int j = 0; j < FN; ++j) {
        const int colL = wn + j * 16 + (lane & 15);
        const float bj = bias[n0 + colL];
        #pragma unroll
        for (int i = 0; i < FM; ++i) {
            #pragma unroll
            for (int r = 0; r < 4; ++r) {
                const int rowL = wm + i * 16 + ((lane >> 4) << 2) + r;
                const int addr = rowL * BN + ((((colL >> 2) ^ (rowL & 7)) << 2) | (colL & 3));
                epi[addr] = acc[i][j][r] + bj;
            }
        }
    }
    __syncthreads();
    #pragma unroll
    for (int k = 0; k < 4; ++k) {
        const int f = k * 512 + tid;            // 128*128/8 = 2048 groups
        const int rr = f >> 4, cc = (f & 15) * 8;
        const int g0 = ((cc >> 2) ^ (rr & 7)) << 2;
        const int g1 = (((cc >> 2) + 1) ^ (rr & 7)) << 2;
        float4 v0 = *(const float4*)&epi[rr * BN + g0];
        float4 v1 = *(const float4*)&epi[rr * BN + g1];
        bf16 tmp[8];
        tmp[0] = __float2bfloat16(v0.x); tmp[1] = __float2bfloat16(v0.y);
        tmp[2] = __float2bfloat16(v0.z); tmp[3] = __float2bfloat16(v0.w);
        tmp[4] = __float2bfloat16(v1.x); tmp[5] = __float2bfloat16(v1.y);
        tmp[6] = __float2bfloat16(v1.z); tmp[7] = __float2bfloat16(v1.w);
        *(bf16x8*)(outb + (size_t)(m0 + rr) * N + n0 + cc) = *(bf16x8*)tmp;
    }
}

// ---------------- FUSED LayerNorm + GEMM (K=768, A resident in LDS, B 2-deep) ----------------
// F32IN: x is f32 (else bf16). EPI 0: bf16 out = acc+bias. EPI 1: loc-softmax -> params.
template<int BM, int BN, int WM, int WN, bool F32IN, int EPI>
__global__ __launch_bounds__(256)
void ln_gemm_kernel(const void* __restrict__ xv, const float* __restrict__ lnw,
                    const float* __restrict__ lnb, const bf16* __restrict__ Bt,
                    const float* __restrict__ bias, const float* __restrict__ refp,
                    void* __restrict__ outv, int M, int N)
{
    constexpr int WAVES_N = BN / WN;
    constexpr int FM = WM / 16, FN = WN / 16;
    constexpr int CWB = BN / 32;
    constexpr int RPW = BM / 4;
    static_assert(BM * BN * 4 <= 2 * BN * 64 * 2, "epi must fit in sB");
    __shared__ __align__(16) bf16 sA[BM * 768];
    __shared__ __align__(16) char sBmem[2 * BN * 64 * 2];
    bf16* sB = (bf16*)sBmem;
    float* epi = (float*)sBmem;

    const int tid = threadIdx.x;
    const int lane = tid & 63;
    const int wave = tid >> 6;

    const int nwgx = gridDim.x;
    const int nwg = nwgx * gridDim.y;
    const int bid = blockIdx.y * nwgx + blockIdx.x;
    const int swz = (bid & 7) * (nwg >> 3) + (bid >> 3);
    const int m0 = (swz / nwgx) * BM;
    const int n0 = (swz % nwgx) * BN;

    const int wm = (wave / WAVES_N) * WM;
    const int wn = (wave % WAVES_N) * WN;
    const int srow = lane >> 3;
    const int scol = ((lane & 7) ^ srow) * 8;

#define STAGEB(tt, half)                                                                           \
    { const int k0_ = (tt) * 64;                                                                   \
      _Pragma("unroll")                                                                            \
      for (int i_ = 0; i_ < CWB; ++i_) {                                                           \
        const int c_ = i_ * 4 + wave;                                                              \
        __builtin_amdgcn_global_load_lds(                                                          \
          (const __attribute__((address_space(1))) void*)(Bt + (size_t)(n0 + c_ * 8 + srow) * 768 + k0_ + scol), \
          (__attribute__((address_space(3))) void*)(sB + (half) * (BN * 64) + c_ * 512), 16, 0, 0); } }

    STAGEB(0, 0);
    STAGEB(1, 1);

    if constexpr (F32IN) {
        const f32x4* w4 = (const f32x4*)lnw;
        const f32x4* b4 = (const f32x4*)lnb;
        f32x4 wv0 = w4[lane], wv1 = w4[64 + lane], wv2 = w4[128 + lane];
        f32x4 bv0 = b4[lane], bv1 = b4[64 + lane], bv2 = b4[128 + lane];
        for (int rr = 0; rr < RPW; ++rr) {
            const int r = wave * RPW + rr;
            const f32x4* xr = (const f32x4*)((const float*)xv + (size_t)(m0 + r) * 768);
            f32x4 f0 = xr[lane], f1 = xr[64 + lane], f2 = xr[128 + lane];
            float s = 0.f, ss = 0.f;
            #pragma unroll
            for (int k = 0; k < 4; ++k) {
                s += f0[k] + f1[k] + f2[k];
                ss += f0[k] * f0[k] + f1[k] * f1[k] + f2[k] * f2[k];
            }
            #pragma unroll
            for (int o = 32; o > 0; o >>= 1) { s += __shfl_down(s, o); ss += __shfl_down(ss, o); }
            s = __shfl(s, 0); ss = __shfl(ss, 0);
            const float mn = s * (1.f / 768);
            const float rs = rsqrtf(ss * (1.f / 768) - mn * mn + 1e-6f);
            const int rx7 = r & 7;
            const int slot = (lane >> 1) & 7;
            const int off = (lane & 1) * 4;
            #pragma unroll
            for (int j = 0; j < 3; ++j) {
                f32x4 fj = (j == 0) ? f0 : (j == 1) ? f1 : f2;
                f32x4 wj = (j == 0) ? wv0 : (j == 1) ? wv1 : wv2;
                f32x4 bj = (j == 0) ? bv0 : (j == 1) ? bv1 : bv2;
                bf16 t4[4];
                #pragma unroll
                for (int k = 0; k < 4; ++k)
                    t4[k] = __float2bfloat16((fj[k] - mn) * rs * wj[k] + bj[k]);
                const int kt = j * 4 + (lane >> 4);
                *(bf16x4*)&sA[r * 768 + kt * 64 + ((slot ^ rx7) << 3) + off] = *(bf16x4*)t4;
            }
        }
    } else {
        const f32x4* w4 = (const f32x4*)lnw;
        const f32x4* b4 = (const f32x4*)lnb;
        f32x4 w80 = w4[lane * 2], w81 = w4[lane * 2 + 1], w44 = w4[128 + lane];
        f32x4 b80 = b4[lane * 2], b81 = b4[lane * 2 + 1], b44 = b4[128 + lane];
        for (int rr = 0; rr < RPW; ++rr) {
            const int r = wave * RPW + rr;
            const bf16* xr = (const bf16*)xv + (size_t)(m0 + r) * 768;
            bf16x8 v8 = *(const bf16x8*)(xr + lane * 8);
            bf16x4 v4 = *(const bf16x4*)(xr + 512 + lane * 4);
            float f[12];
            #pragma unroll
            for (int k = 0; k < 8; ++k) f[k] = bf2f(v8[k]);
            #pragma unroll
            for (int k = 0; k < 4; ++k) f[8 + k] = bf2f(v4[k]);
            float s = 0.f, ss = 0.f;
            #pragma unroll
            for (int k = 0; k < 12; ++k) { s += f[k]; ss += f[k] * f[k]; }
            #pragma unroll
            for (int o = 32; o > 0; o >>= 1) { s += __shfl_down(s, o); ss += __shfl_down(ss, o); }
            s = __shfl(s, 0); ss = __shfl(ss, 0);
            const float mn = s * (1.f / 768);
            const float rs = rsqrtf(ss * (1.f / 768) - mn * mn + 1e-6f);
            const int rx7 = r & 7;
            bf16 t8[8];
            #pragma unroll
            for (int k = 0; k < 4; ++k) t8[k] = __float2bfloat16((f[k] - mn) * rs * w80[k] + b80[k]);
            #pragma unroll
            for (int k = 0; k < 4; ++k) t8[4 + k] = __float2bfloat16((f[4 + k] - mn) * rs * w81[k] + b81[k]);
            *(bf16x8*)&sA[r * 768 + (lane >> 3) * 64 + (((lane & 7) ^ rx7) << 3)] = *(bf16x8*)t8;
            bf16 t4[4];
            #pragma unroll
            for (int k = 0; k < 4; ++k) t4[k] = __float2bfloat16((f[8 + k] - mn) * rs * w44[k] + b44[k]);
            *(bf16x4*)&sA[r * 768 + (8 + (lane >> 4)) * 64 + ((((lane >> 1) & 7) ^ rx7) << 3) + (lane & 1) * 4]
                = *(bf16x4*)t4;
        }
    }
    asm volatile("s_waitcnt lgkmcnt(0)" ::: "memory");

    f32x4 acc[FM][FN] = {};
    #pragma unroll
    for (int t = 0; t < 12; ++t) {
        const int half = t & 1;
        if (t + 1 < 12) wait_vmcnt<CWB>();
        else            wait_vmcnt<0>();
        __builtin_amdgcn_s_barrier();
        const bf16* cB = sB + half * (BN * 64);
        #pragma unroll
        for (int kki = 0; kki < 2; ++kki) {
            const int kslot = kki * 4 + (lane >> 4);
            bf16x8 aF[FM], bF[FN];
            #pragma unroll
            for (int i = 0; i < FM; ++i) {
                const int row = wm + i * 16 + (lane & 15);
                aF[i] = *(const bf16x8*)(&sA[row * 768 + t * 64 + ((kslot ^ (row & 7)) * 8)]);
            }
            #pragma unroll
            for (int j = 0; j < FN; ++j) {
                const int row = wn + j * 16 + (lane & 15);
                bF[j] = *(const bf16x8*)(&cB[row * 64 + ((kslot ^ (row & 7)) * 8)]);
            }
            #pragma unroll
            for (int i = 0; i < FM; ++i) {
                #pragma unroll
                for (int j = 0; j < FN; ++j)
                    acc[i][j] = __builtin_amdgcn_mfma_f32_16x16x32_bf16(aF[i], bF[j], acc[i][j], 0, 0, 0);
            }
        }
        asm volatile("s_waitcnt lgkmcnt(0)" ::: "memory");
        __builtin_amdgcn_s_barrier();
        if (t + 2 < 12) STAGEB(t + 2, half);
    }
#undef STAGEB

    #pragma unroll
    for (int j = 0; j < FN; ++j) {
        const int colL = wn + j * 16 + (lane & 15);
        const float bj = bias[n0 + colL];
        #pragma unroll
        for (int i = 0; i < FM; ++i) {
            #pragma unroll
            for (int r = 0; r < 4; ++r) {
                const int rowL = wm + i * 16 + ((lane >> 4) << 2) + r;
                const int addr = rowL * BN + ((((colL >> 2) ^ (rowL & 7)) << 2) | (colL & 3));
                epi[addr] = acc[i][j][r] + bj;
            }
        }
    }
    __syncthreads();

    if constexpr (EPI == 1) {
        if (tid < BM * NHEADS) {
            const int rowL = tid & (BM - 1);
            const int h = tid / BM;
            auto erd = [&](int col) -> float {
                return epi[rowL * BN + ((((col >> 2) ^ (rowL & 7)) << 2) | (col & 3))];
            };
            float l0 = erd(48 + h * 4 + 0), l1 = erd(48 + h * 4 + 1);
            float l2 = erd(48 + h * 4 + 2), l3 = erd(48 + h * 4 + 3);
            float mx = fmaxf(fmaxf(l0, l1), fmaxf(l2, l3));
            float e0 = expf(l0 - mx), e1 = expf(l1 - mx), e2 = expf(l2 - mx), e3 = expf(l3 - mx);
            float inv = 1.f / (e0 + e1 + e2 + e3);
            float ee[4] = {e0, e1, e2, e3};
            const float rx = refp[(size_t)(m0 + rowL) * 2];
            const float ry = refp[(size_t)(m0 + rowL) * 2 + 1];
            float4* pp = (float4*)outv + ((size_t)(m0 + rowL) * NHEADS + h) * 4;
            #pragma unroll
            for (int p = 0; p < 4; ++p) {
                float ox = erd(h * 8 + p * 2), oy = erd(h * 8 + p * 2 + 1);
                pp[p] = make_float4(rx + ox * (1.f / WLVL), ry + oy * (1.f / HLVL), ee[p] * inv, 0.f);
            }
        }
    } else {
        constexpr int GPR8 = BN / 8;
        constexpr int GPT8 = (BM * BN / 8) / 256;
        #pragma unroll
        for (int k = 0; k < GPT8; ++k) {
            const int f = k * 256 + tid;
            const int rr = f / GPR8, cc = (f % GPR8) * 8;
            const int g0 = ((cc >> 2) ^ (rr & 7)) << 2;
            const int g1 = (((cc >> 2) + 1) ^ (rr & 7)) << 2;
            float4 v0 = *(const float4*)&epi[rr * BN + g0];
            float4 v1 = *(const float4*)&epi[rr * BN + g1];
            bf16 tmp[8];
            tmp[0] = __float2bfloat16(v0.x); tmp[1] = __float2bfloat16(v0.y);
            tmp[2] = __float2bfloat16(v0.z); tmp[3] = __float2bfloat16(v0.w);
            tmp[4] = __float2bfloat16(v1.x); tmp[5] = __float2bfloat16(v1.y);
            tmp[6] = __float2bfloat16(v1.z); tmp[7] = __float2bfloat16(v1.w);
            *(bf16x8*)((bf16*)outv + (size_t)(m0 + rr) * N + n0 + cc) = *(bf16x8*)tmp;
        }
    }
}

// ---------------- bilinear sample: branchless, image->XCD pinned, HEAD-MAJOR within image --------
__global__ __launch_bounds__(256)
void sampler_kernel(const bf16* __restrict__ value, const float4* __restrict__ params,
                    bf16* __restrict__ attn_in)
{
    const int tid = threadIdx.x;
    const int b = blockIdx.x & 7;                   // image == XCD
    const int local = blockIdx.x >> 3;              // [0, 1152)
    const int h = local / 192;                      // head-major
    const int qc = local - h * 192;                 // q-chunk (16 q each)
    const int bl = b * LQ + qc * 16 + (tid >> 4);   // global query index
    const int g = bl * NHEADS + h;                  // query-head index
    const int lane16 = tid & 15;
    const bf16* vh = value + (size_t)b * LIN * CC + h * DHEAD + lane16 * 8;

    int offs[16];
    float wgt[16];
    #pragma unroll
    for (int p = 0; p < NPTS; ++p) {
        float4 pr = params[(size_t)g * 4 + p];
        float x = pr.x * (float)WLVL - 0.5f;
        float y = pr.y * (float)HLVL - 0.5f;
        float x0f = floorf(x), y0f = floorf(y);
        float wx1 = x - x0f, wy1 = y - y0f;
        float wx0 = 1.f - wx1, wy0 = 1.f - wy1;
        int x0 = (int)x0f, y0 = (int)y0f;
        #pragma unroll
        for (int dy = 0; dy < 2; ++dy) {
            const int yi = y0 + dy;
            const int yc = min(max(yi, 0), HLVL - 1);
            const float wy = (dy ? wy1 : wy0) * ((yi >= 0 && yi < HLVL) ? pr.z : 0.f);
            #pragma unroll
            for (int dx = 0; dx < 2; ++dx) {
                const int xi = x0 + dx;
                const int xc = min(max(xi, 0), WLVL - 1);
                const int idx = p * 4 + dy * 2 + dx;
                offs[idx] = (yc * WLVL + xc) * CC;
                wgt[idx] = wy * (dx ? wx1 : wx0) * ((xi >= 0 && xi < WLVL) ? 1.f : 0.f);
            }
        }
    }
    bf16x8 v[16];
    #pragma unroll
    for (int i = 0; i < 16; ++i) v[i] = *(const bf16x8*)(vh + offs[i]);
    float acc[8] = {};
    #pragma unroll
    for (int i = 0; i < 16; ++i) {
        #pragma unroll
        for (int j = 0; j < 8; ++j)
            acc[j] += wgt[i] * bf2f(v[i][j]);
    }
    bf16 tmp[8];
    #pragma unroll
    for (int j = 0; j < 8; ++j) tmp[j] = __float2bfloat16(acc[j]);
    *(bf16x8*)(attn_in + (size_t)bl * CC + h * DHEAD + lane16 * 8) = *(bf16x8*)tmp;
}

// ---------------- depthwise 3x3 conv + bias + exact GELU (bf16 in/out, 4ch/thread) ----------------
__global__ __launch_bounds__(192)
void dwconv_gelu_kernel(const bf16* __restrict__ z, const float* __restrict__ dw_w,
                        const float* __restrict__ dw_b, bf16* __restrict__ g)
{
    const int tp = threadIdx.x / 48;
    const int tc = threadIdx.x % 48;
    const int m = blockIdx.x * 4 + tp;
    const int c = tc * 4;
    const int pix = m & 1023;
    const int h = pix >> 5, w = pix & 31;
    float acc[4];
    #pragma unroll
    for (int j = 0; j < 4; ++j) acc[j] = dw_b[c + j];
    #pragma unroll
    for (int dy = -1; dy <= 1; ++dy) {
        int hh2 = h + dy;
        if (hh2 < 0 || hh2 >= 32) continue;
        #pragma unroll
        for (int dx = -1; dx <= 1; ++dx) {
            int ww2 = w + dx;
            if (ww2 < 0 || ww2 >= 32) continue;
            bf16x4 vv = *(const bf16x4*)&z[(size_t)(m + dy * 32 + dx) * HID + c];
            #pragma unroll
            for (int j = 0; j < 4; ++j)
                acc[j] += bf2f(vv[j]) * dw_w[(c + j) * 9 + (dy + 1) * 3 + (dx + 1)];
        }
    }
    bf16 tmp[4];
    #pragma unroll
    for (int j = 0; j < 4; ++j) {
        float ge = acc[j] * 0.5f * (1.f + erff(acc[j] * 0.70710678118f));
        tmp[j] = __float2bfloat16(ge);
    }
    *(bf16x4*)&g[(size_t)m * HID + c] = *(bf16x4*)tmp;
}

extern "C" void kernel_launch(void* const* d_in, const int* in_sizes, int n_in,
                              void* d_out, int out_size, void* d_ws, size_t ws_size,
                              hipStream_t stream)
{
    const float* query = (const float*)d_in[0];
    const float* refp  = (const float*)d_in[1];
    const float* feat  = (const float*)d_in[2];
    const float* qn_w = (const float*)d_in[7];
    const float* qn_b = (const float*)d_in[8];
    const float* fn_w = (const float*)d_in[9];
    const float* fn_b = (const float*)d_in[10];
    const float* so_w = (const float*)d_in[11];
    const float* so_b = (const float*)d_in[12];
    const float* aw_w = (const float*)d_in[13];
    const float* aw_b = (const float*)d_in[14];
    const float* vp_w = (const float*)d_in[15];
    const float* vp_b = (const float*)d_in[16];
    const float* op_w = (const float*)d_in[17];
    const float* op_b = (const float*)d_in[18];
    const float* ffn_w = (const float*)d_in[19];
    const float* ffn_b = (const float*)d_in[20];
    const float* fc1_w = (const float*)d_in[21];
    const float* fc1_b = (const float*)d_in[22];
    const float* dw_w = (const float*)d_in[23];
    const float* dw_b = (const float*)d_in[24];
    const float* fc2_w = (const float*)d_in[25];
    const float* fc2_b = (const float*)d_in[26];
    float* out = (float*)d_out;

    if (ws_size < (size_t)125829632) return;
    char* ws = (char*)d_ws;
    bf16* vp_wt   = (bf16*)(ws + 0);
    bf16* op_wt   = (bf16*)(ws + 1179648);
    bf16* fc1_wt  = (bf16*)(ws + 2359296);
    bf16* fc2_wt  = (bf16*)(ws + 2654208);
    bf16* dots_wt = (bf16*)(ws + 2949120);
    float* dots_b = (float*)(ws + 3145728);
    char* paramsR = ws + 3146240;
    char* dotsR   = ws + 12583424;
    char* regA = ws + 25166336;
    char* regB = ws + 75497984;
    float4* params = (float4*)paramsR;
    bf16* g        = (bf16*)paramsR;
    bf16* z        = (bf16*)dotsR;
    bf16* f_ln    = (bf16*)regA;
    bf16* attn_in = (bf16*)regA;
    bf16* value = (bf16*)regB;
    bf16* s_bf  = (bf16*)regB;

    // ---- prep (weights) + LN(feat), one launch ----
    prep_kernel<<<744 + FROWS / 4, 256, 0, stream>>>(
        vp_w, op_w, fc1_w, fc2_w, so_w, so_b, aw_w, aw_b, feat, fn_w, fn_b,
        vp_wt, op_wt, fc1_wt, fc2_wt, dots_wt, dots_b, f_ln);

    // ---- MSDeformAttn ----
    ln_gemm_kernel<32, 128, 16, 64, true, 1><<<dim3(1, BLTOT / 32), 256, 0, stream>>>(
        query, qn_w, qn_b, dots_wt, dots_b, refp, params, BLTOT, 128);
    gemm_value_kernel<<<dim3(6, FROWS / 128), 512, 0, stream>>>(
        f_ln, vp_wt, vp_b, value, FROWS, 768, 768);
    sampler_kernel<<<(BLTOT * NHEADS) / 16, 256, 0, stream>>>(value, params, attn_in);
    gemm_kernel<32, 128, 16, 64, 3><<<dim3(6, BLTOT / 32), 256, 0, stream>>>(
        attn_in, op_wt, op_b, query, s_bf, BLTOT, 768, 768);    // s_bf = query + attn (bf16)

    // ---- ConvFFN ----
    ln_gemm_kernel<32, 64, 32, 16, false, 0><<<dim3(3, BLTOT / 32), 256, 0, stream>>>(
        s_bf, ffn_w, ffn_b, fc1_wt, fc1_b, nullptr, z, BLTOT, HID);
    dwconv_gelu_kernel<<<BLTOT / 4, 192, 0, stream>>>(z, dw_w, dw_b, g);
    gemm_kernel<32, 128, 16, 64, 4><<<dim3(6, BLTOT / 32), 256, 0, stream>>>(
        g, fc2_wt, fc2_b, s_bf, out, BLTOT, 768, HID);          // out = s_bf + ffn (f32)
}

// Round 12
// 303.426 us; speedup vs baseline: 1.0399x; 1.0399x over previous
//
#include <hip/hip_runtime.h>
#include <hip/hip_bf16.h>
#include <math.h>

typedef __hip_bfloat16 bf16;
typedef short bf16x8 __attribute__((ext_vector_type(8)));
typedef short bf16x4 __attribute__((ext_vector_type(4)));
typedef float f32x4 __attribute__((ext_vector_type(4)));

#define NB 8
#define LQ 3072
#define CC 768
#define NHEADS 6
#define NPTS 4
#define DHEAD 128
#define HLVL 64
#define WLVL 64
#define LIN 4096
#define HID 192
#define BLTOT 24576   // NB*LQ
#define FROWS 32768   // NB*LIN

__device__ __forceinline__ float bf2f(short u)
{ return __uint_as_float(((unsigned)(unsigned short)u) << 16); }

template<int N_>
__device__ __forceinline__ void wait_vmcnt()
{
    if constexpr (N_ == 0)      asm volatile("s_waitcnt vmcnt(0)" ::: "memory");
    else if constexpr (N_ == 2) asm volatile("s_waitcnt vmcnt(2)" ::: "memory");
    else if constexpr (N_ == 4) asm volatile("s_waitcnt vmcnt(4)" ::: "memory");
    else if constexpr (N_ == 5) asm volatile("s_waitcnt vmcnt(5)" ::: "memory");
    else if constexpr (N_ == 6) asm volatile("s_waitcnt vmcnt(6)" ::: "memory");
    else if constexpr (N_ == 8) asm volatile("s_waitcnt vmcnt(8)" ::: "memory");
    else static_assert(N_ == 0, "add a vmcnt case");
}

// ---------------- merged prep: 4 weight transposes + dots weight + LN(feat), one launch ----------
__device__ __forceinline__ void wt_tile(float (*t)[65], const float* __restrict__ src,
                                        bf16* __restrict__ dst, int K, int N, int tn0, int tk0)
{
    const int r = threadIdx.x >> 6, c = threadIdx.x & 63;
    #pragma unroll
    for (int i = 0; i < 16; ++i)
        t[i * 4 + r][c] = src[(size_t)(tk0 + i * 4 + r) * N + tn0 + c];
    __syncthreads();
    #pragma unroll
    for (int i = 0; i < 16; ++i)
        dst[(size_t)(tn0 + i * 4 + r) * K + tk0 + c] = __float2bfloat16(t[c][i * 4 + r]);
}

__global__ __launch_bounds__(256)
void prep_kernel(const float* __restrict__ vp_w, const float* __restrict__ op_w,
                 const float* __restrict__ fc1_w, const float* __restrict__ fc2_w,
                 const float* __restrict__ so_w, const float* __restrict__ so_b,
                 const float* __restrict__ aw_w, const float* __restrict__ aw_b,
                 const float* __restrict__ feat, const float* __restrict__ fn_w,
                 const float* __restrict__ fn_b,
                 bf16* __restrict__ vp_wt, bf16* __restrict__ op_wt,
                 bf16* __restrict__ fc1_wt, bf16* __restrict__ fc2_wt,
                 bf16* __restrict__ dots_wt, float* __restrict__ db,
                 bf16* __restrict__ f_ln)
{
    __shared__ float t[64][65];
    int b = blockIdx.x;
    if (b < 144)      wt_tile(t, vp_w, vp_wt, 768, 768, (b % 12) * 64, (b / 12) * 64);
    else if (b < 288) { b -= 144; wt_tile(t, op_w, op_wt, 768, 768, (b % 12) * 64, (b / 12) * 64); }
    else if (b < 324) { b -= 288; wt_tile(t, fc1_w, fc1_wt, 768, 192, (b % 3) * 64, (b / 3) * 64); }
    else if (b < 360) { b -= 324; wt_tile(t, fc2_w, fc2_wt, 192, 768, (b % 12) * 64, (b / 12) * 64); }
    else if (b < 744) {
        b -= 360;
        int i = b * 256 + threadIdx.x;          // over 128*768
        if (i < 128 * 768) {
            int n = i / 768, k = i - n * 768;
            float v = 0.f;
            if (n < 48) v = so_w[(size_t)k * 48 + n];
            else if (n < 72) v = aw_w[(size_t)k * 24 + (n - 48)];
            dots_wt[i] = __float2bfloat16(v);
        }
        if (i < 128) {
            float bv = 0.f;
            if (i < 48) bv = so_b[i];
            else if (i < 72) bv = aw_b[i - 48];
            db[i] = bv;
        }
    } else {
        // LN(feat) -> f_ln, wave per row
        const int row = (b - 744) * 4 + (threadIdx.x >> 6);
        const int lane = threadIdx.x & 63;
        const f32x4* xr = (const f32x4*)(feat + (size_t)row * CC);
        f32x4 f0 = xr[lane], f1 = xr[64 + lane], f2 = xr[128 + lane];
        float s = 0.f, ss = 0.f;
        #pragma unroll
        for (int k = 0; k < 4; ++k) {
            s += f0[k] + f1[k] + f2[k];
            ss += f0[k] * f0[k] + f1[k] * f1[k] + f2[k] * f2[k];
        }
        #pragma unroll
        for (int o = 32; o > 0; o >>= 1) { s += __shfl_down(s, o); ss += __shfl_down(ss, o); }
        s = __shfl(s, 0); ss = __shfl(ss, 0);
        const float m = s * (1.f / CC);
        const float rs = rsqrtf(ss * (1.f / CC) - m * m + 1e-6f);
        const f32x4* w4 = (const f32x4*)fn_w;
        const f32x4* b4 = (const f32x4*)fn_b;
        bf16* orow = f_ln + (size_t)row * CC;
        #pragma unroll
        for (int j = 0; j < 3; ++j) {
            f32x4 fj = (j == 0) ? f0 : (j == 1) ? f1 : f2;
            f32x4 wj = w4[j * 64 + lane], bj = b4[j * 64 + lane];
            bf16 t4[4];
            #pragma unroll
            for (int k = 0; k < 4; ++k) t4[k] = __float2bfloat16((fj[k] - m) * rs * wj[k] + bj[k]);
            *(bf16x4*)(orow + j * 256 + lane * 4) = *(bf16x4*)t4;
        }
    }
}

// ---------------- bf16 MFMA GEMM (256 thr): 2-deep pipelined, XOR-swizzled LDS ----------------
// MODE 0: bf16 out = acc+bias
// MODE 3: bf16 out = acc+bias+res_f32   (res prefetched to regs)
// MODE 4: f32  out = acc+bias+res_bf16  (res prefetched to regs)
template<int BM, int BN, int WM, int WN, int MODE>
__global__ __launch_bounds__(256)
void gemm_kernel(const bf16* __restrict__ A, const bf16* __restrict__ Bt,
                 const float* __restrict__ bias, const void* __restrict__ resv,
                 void* __restrict__ outv, int M, int N, int K)
{
    constexpr int WAVES_N = BN / WN;
    constexpr int FM = WM / 16, FN = WN / 16;
    constexpr int CWA = BM / 32;
    constexpr int CWB = BN / 32;
    constexpr int LPT = CWA + CWB;
    constexpr int ABYTES = BM * 256;
    constexpr int DBUF_BYTES = (BM + BN) * 256;
    constexpr int EPI_BYTES = BM * BN * 4;
    constexpr size_t SMEM_BYTES = DBUF_BYTES > EPI_BYTES ? DBUF_BYTES : EPI_BYTES;
    __shared__ __align__(16) char smem[SMEM_BYTES];
    bf16* sA = (bf16*)smem;
    bf16* sB = (bf16*)(smem + ABYTES);
    float* epi = (float*)smem;

    const int tid = threadIdx.x;
    const int lane = tid & 63;
    const int wave = tid >> 6;

    const int nwgx = gridDim.x;
    const int nwg = nwgx * gridDim.y;
    const int bid = blockIdx.y * nwgx + blockIdx.x;
    const int swz = (bid & 7) * (nwg >> 3) + (bid >> 3);
    const int m0 = (swz / nwgx) * BM;
    const int n0 = (swz % nwgx) * BN;

    const int wm = (wave / WAVES_N) * WM;
    const int wn = (wave % WAVES_N) * WN;

    const int srow = lane >> 3;
    const int scol = ((lane & 7) ^ srow) * 8;

    constexpr int GPR8 = BN / 8;
    constexpr int GPT8 = (BM * BN / 8) / 256;
    constexpr int QPR4 = BN / 4;
    constexpr int QPT4 = (BM * BN / 4) / 256;
    float4 pr0[GPT8], pr1[GPT8];
    bf16x4 prb[QPT4];
    if constexpr (MODE == 3) {
        const float* resf = (const float*)resv;
        #pragma unroll
        for (int k = 0; k < GPT8; ++k) {
            const int f = k * 256 + tid;
            const int rr = f / GPR8, cc = (f % GPR8) * 8;
            const size_t gidx = (size_t)(m0 + rr) * N + n0 + cc;
            pr0[k] = *(const float4*)&resf[gidx];
            pr1[k] = *(const float4*)&resf[gidx + 4];
        }
    }
    if constexpr (MODE == 4) {
        const bf16* resb = (const bf16*)resv;
        #pragma unroll
        for (int k = 0; k < QPT4; ++k) {
            const int f = k * 256 + tid;
            const int rr = f / QPR4, cc = (f % QPR4) * 4;
            prb[k] = *(const bf16x4*)&resb[(size_t)(m0 + rr) * N + n0 + cc];
        }
    }

#define STAGE(tt, half)                                                                            \
    { const int k0_ = (tt) * 64;                                                                   \
      _Pragma("unroll")                                                                            \
      for (int i_ = 0; i_ < CWA; ++i_) {                                                           \
        const int c_ = i_ * 4 + wave;                                                              \
        __builtin_amdgcn_global_load_lds(                                                          \
          (const __attribute__((address_space(1))) void*)(A + (size_t)(m0 + c_ * 8 + srow) * K + k0_ + scol), \
          (__attribute__((address_space(3))) void*)(sA + (half) * (BM * 64) + c_ * 512), 16, 0, 0); } \
      _Pragma("unroll")                                                                            \
      for (int i_ = 0; i_ < CWB; ++i_) {                                                           \
        const int c_ = i_ * 4 + wave;                                                              \
        __builtin_amdgcn_global_load_lds(                                                          \
          (const __attribute__((address_space(1))) void*)(Bt + (size_t)(n0 + c_ * 8 + srow) * K + k0_ + scol), \
          (__attribute__((address_space(3))) void*)(sB + (half) * (BN * 64) + c_ * 512), 16, 0, 0); } }

    f32x4 acc[FM][FN] = {};
    const int nt = K >> 6;

    STAGE(0, 0);
    STAGE(1, 1);

    for (int t = 0; t < nt; ++t) {
        const int half = t & 1;
        if (t + 1 < nt) wait_vmcnt<LPT>();
        else            wait_vmcnt<0>();
        __builtin_amdgcn_s_barrier();
        const bf16* cA = sA + half * (BM * 64);
        const bf16* cB = sB + half * (BN * 64);
        #pragma unroll
        for (int kki = 0; kki < 2; ++kki) {
            const int kslot = kki * 4 + (lane >> 4);
            bf16x8 aF[FM], bF[FN];
            #pragma unroll
            for (int i = 0; i < FM; ++i) {
                const int row = wm + i * 16 + (lane & 15);
                aF[i] = *(const bf16x8*)(&cA[row * 64 + ((kslot ^ (row & 7)) * 8)]);
            }
            #pragma unroll
            for (int j = 0; j < FN; ++j) {
                const int row = wn + j * 16 + (lane & 15);
                bF[j] = *(const bf16x8*)(&cB[row * 64 + ((kslot ^ (row & 7)) * 8)]);
            }
            #pragma unroll
            for (int i = 0; i < FM; ++i) {
                #pragma unroll
                for (int j = 0; j < FN; ++j)
                    acc[i][j] = __builtin_amdgcn_mfma_f32_16x16x32_bf16(aF[i], bF[j], acc[i][j], 0, 0, 0);
            }
        }
        asm volatile("s_waitcnt lgkmcnt(0)" ::: "memory");
        __builtin_amdgcn_s_barrier();
        if (t + 2 < nt) STAGE(t + 2, half);
    }
#undef STAGE

    #pragma unroll
    for (int j = 0; j < FN; ++j) {
        const int colL = wn + j * 16 + (lane & 15);
        const float bj = bias[n0 + colL];
        #pragma unroll
        for (int i = 0; i < FM; ++i) {
            #pragma unroll
            for (int r = 0; r < 4; ++r) {
                const int rowL = wm + i * 16 + ((lane >> 4) << 2) + r;
                const int addr = rowL * BN + ((((colL >> 2) ^ (rowL & 7)) << 2) | (colL & 3));
                epi[addr] = acc[i][j][r] + bj;
            }
        }
    }
    __syncthreads();

    if constexpr (MODE == 0 || MODE == 3) {
        #pragma unroll
        for (int k = 0; k < GPT8; ++k) {
            const int f = k * 256 + tid;
            const int rr = f / GPR8, cc = (f % GPR8) * 8;
            const int g0 = ((cc >> 2) ^ (rr & 7)) << 2;
            const int g1 = (((cc >> 2) + 1) ^ (rr & 7)) << 2;
            float4 v0 = *(const float4*)&epi[rr * BN + g0];
            float4 v1 = *(const float4*)&epi[rr * BN + g1];
            if constexpr (MODE == 3) {
                v0.x += pr0[k].x; v0.y += pr0[k].y; v0.z += pr0[k].z; v0.w += pr0[k].w;
                v1.x += pr1[k].x; v1.y += pr1[k].y; v1.z += pr1[k].z; v1.w += pr1[k].w;
            }
            bf16 tmp[8];
            tmp[0] = __float2bfloat16(v0.x); tmp[1] = __float2bfloat16(v0.y);
            tmp[2] = __float2bfloat16(v0.z); tmp[3] = __float2bfloat16(v0.w);
            tmp[4] = __float2bfloat16(v1.x); tmp[5] = __float2bfloat16(v1.y);
            tmp[6] = __float2bfloat16(v1.z); tmp[7] = __float2bfloat16(v1.w);
            *(bf16x8*)((bf16*)outv + (size_t)(m0 + rr) * N + n0 + cc) = *(bf16x8*)tmp;
        }
    } else {
        #pragma unroll
        for (int k = 0; k < QPT4; ++k) {
            const int f = k * 256 + tid;
            const int rr = f / QPR4, cc = (f % QPR4) * 4;
            const int gs = ((cc >> 2) ^ (rr & 7)) << 2;
            float4 v = *(const float4*)&epi[rr * BN + gs];
            if constexpr (MODE == 4) {
                v.x += bf2f(prb[k][0]); v.y += bf2f(prb[k][1]);
                v.z += bf2f(prb[k][2]); v.w += bf2f(prb[k][3]);
            }
            *(float4*)&((float*)outv)[(size_t)(m0 + rr) * N + n0 + cc] = v;
        }
    }
}

// ---------------- value GEMM: 512 threads, 128x128 tile, HEAD-MAJOR output ----------------
// outb layout: (b, head, pix, 128) -- each head-slice is a contiguous 1MB block.
__global__ __launch_bounds__(512)
void gemm_value_kernel(const bf16* __restrict__ A, const bf16* __restrict__ Bt,
                       const float* __restrict__ bias, bf16* __restrict__ outb,
                       int M, int N, int K)
{
    constexpr int BM = 128, BN = 128;
    constexpr int FM = 2, FN = 4;               // wave tile 32x64; 8 waves = 4x2
    constexpr int LPT = 4;                      // 2 A + 2 B chunks per wave per tile
    __shared__ __align__(16) char smem[2 * (BM + BN) * 128];   // 64KB
    bf16* sA = (bf16*)smem;
    bf16* sB = (bf16*)(smem + 2 * BM * 128);
    float* epi = (float*)smem;                  // 64KB epilogue reuse

    const int tid = threadIdx.x;
    const int lane = tid & 63;
    const int wave = tid >> 6;

    const int nwgx = gridDim.x;
    const int nwg = nwgx * gridDim.y;
    const int bid = blockIdx.y * nwgx + blockIdx.x;
    const int swz = (bid & 7) * (nwg >> 3) + (bid >> 3);
    const int m0 = (swz / nwgx) * BM;
    const int n0 = (swz % nwgx) * BN;

    const int wm = (wave >> 1) * 32;
    const int wn = (wave & 1) * 64;
    const int srow = lane >> 3;
    const int scol = ((lane & 7) ^ srow) * 8;

#define STAGEV(tt, half)                                                                           \
    { const int k0_ = (tt) * 64;                                                                   \
      _Pragma("unroll")                                                                            \
      for (int i_ = 0; i_ < 2; ++i_) {                                                             \
        const int c_ = i_ * 8 + wave;                                                              \
        __builtin_amdgcn_global_load_lds(                                                          \
          (const __attribute__((address_space(1))) void*)(A + (size_t)(m0 + c_ * 8 + srow) * K + k0_ + scol), \
          (__attribute__((address_space(3))) void*)(sA + (half) * (BM * 64) + c_ * 512), 16, 0, 0); } \
      _Pragma("unroll")                                                                            \
      for (int i_ = 0; i_ < 2; ++i_) {                                                             \
        const int c_ = i_ * 8 + wave;                                                              \
        __builtin_amdgcn_global_load_lds(                                                          \
          (const __attribute__((address_space(1))) void*)(Bt + (size_t)(n0 + c_ * 8 + srow) * K + k0_ + scol), \
          (__attribute__((address_space(3))) void*)(sB + (half) * (BN * 64) + c_ * 512), 16, 0, 0); } }

    f32x4 acc[FM][FN] = {};
    const int nt = K >> 6;

    STAGEV(0, 0);
    STAGEV(1, 1);

    for (int t = 0; t < nt; ++t) {
        const int half = t & 1;
        if (t + 1 < nt) wait_vmcnt<LPT>();
        else            wait_vmcnt<0>();
        __builtin_amdgcn_s_barrier();
        const bf16* cA = sA + half * (BM * 64);
        const bf16* cB = sB + half * (BN * 64);
        #pragma unroll
        for (int kki = 0; kki < 2; ++kki) {
            const int kslot = kki * 4 + (lane >> 4);
            bf16x8 aF[FM], bF[FN];
            #pragma unroll
            for (int i = 0; i < FM; ++i) {
                const int row = wm + i * 16 + (lane & 15);
                aF[i] = *(const bf16x8*)(&cA[row * 64 + ((kslot ^ (row & 7)) * 8)]);
            }
            #pragma unroll
            for (int j = 0; j < FN; ++j) {
                const int row = wn + j * 16 + (lane & 15);
                bF[j] = *(const bf16x8*)(&cB[row * 64 + ((kslot ^ (row & 7)) * 8)]);
            }
            #pragma unroll
            for (int i = 0; i < FM; ++i) {
                #pragma unroll
                for (int j = 0; j < FN; ++j)
                    acc[i][j] = __builtin_amdgcn_mfma_f32_16x16x32_bf16(aF[i], bF[j], acc[i][j], 0, 0, 0);
            }
        }
        asm volatile("s_waitcnt lgkmcnt(0)" ::: "memory");
        __builtin_amdgcn_s_barrier();
        if (t + 2 < nt) STAGEV(t + 2, half);
    }
#undef STAGEV

    // ---- epilogue: acc -> LDS (swizzled) -> bf16x8 head-major stores ----
    #pragma unroll
    for (int j = 0; j < FN; ++j) {
        const int colL = wn + j * 16 + (lane & 15);
        const float bj = bias[n0 + colL];
        #pragma unroll
        for (int i = 0; i < FM; ++i) {
            #pragma unroll
            for (int r = 0; r < 4; ++r) {
                const int rowL = wm + i * 16 + ((lane >> 4) << 2) + r;
                const int addr = rowL * BN + ((((colL >> 2) ^ (rowL & 7)) << 2) | (colL & 3));
                epi[addr] = acc[i][j][r] + bj;
            }
        }
    }
    __syncthreads();
    // n0 is a multiple of 128 = DHEAD -> this block covers exactly one head.
    const int hd = n0 >> 7;
    const int img = m0 >> 12;                   // 4096 rows per image
    const int pix0 = m0 & 4095;
    bf16* obase = outb + (((size_t)img * NHEADS + hd) * LIN + pix0) * DHEAD;
    #pragma unroll
    for (int k = 0; k < 4; ++k) {
        const int f = k * 512 + tid;            // 128*128/8 = 2048 groups
        const int rr = f >> 4, cc = (f & 15) * 8;
        const int g0 = ((cc >> 2) ^ (rr & 7)) << 2;
        const int g1 = (((cc >> 2) + 1) ^ (rr & 7)) << 2;
        float4 v0 = *(const float4*)&epi[rr * BN + g0];
        float4 v1 = *(const float4*)&epi[rr * BN + g1];
        bf16 tmp[8];
        tmp[0] = __float2bfloat16(v0.x); tmp[1] = __float2bfloat16(v0.y);
        tmp[2] = __float2bfloat16(v0.z); tmp[3] = __float2bfloat16(v0.w);
        tmp[4] = __float2bfloat16(v1.x); tmp[5] = __float2bfloat16(v1.y);
        tmp[6] = __float2bfloat16(v1.z); tmp[7] = __float2bfloat16(v1.w);
        *(bf16x8*)(obase + (size_t)rr * DHEAD + cc) = *(bf16x8*)tmp;
    }
}

// ---------------- FUSED LayerNorm + GEMM (K=768, A resident in LDS, B 2-deep) ----------------
// F32IN: x is f32 (else bf16). EPI 0: bf16 out = acc+bias. EPI 1: loc-softmax -> params.
template<int BM, int BN, int WM, int WN, bool F32IN, int EPI>
__global__ __launch_bounds__(256)
void ln_gemm_kernel(const void* __restrict__ xv, const float* __restrict__ lnw,
                    const float* __restrict__ lnb, const bf16* __restrict__ Bt,
                    const float* __restrict__ bias, const float* __restrict__ refp,
                    void* __restrict__ outv, int M, int N)
{
    constexpr int WAVES_N = BN / WN;
    constexpr int FM = WM / 16, FN = WN / 16;
    constexpr int CWB = BN / 32;
    constexpr int RPW = BM / 4;
    static_assert(BM * BN * 4 <= 2 * BN * 64 * 2, "epi must fit in sB");
    __shared__ __align__(16) bf16 sA[BM * 768];
    __shared__ __align__(16) char sBmem[2 * BN * 64 * 2];
    bf16* sB = (bf16*)sBmem;
    float* epi = (float*)sBmem;

    const int tid = threadIdx.x;
    const int lane = tid & 63;
    const int wave = tid >> 6;

    const int nwgx = gridDim.x;
    const int nwg = nwgx * gridDim.y;
    const int bid = blockIdx.y * nwgx + blockIdx.x;
    const int swz = (bid & 7) * (nwg >> 3) + (bid >> 3);
    const int m0 = (swz / nwgx) * BM;
    const int n0 = (swz % nwgx) * BN;

    const int wm = (wave / WAVES_N) * WM;
    const int wn = (wave % WAVES_N) * WN;
    const int srow = lane >> 3;
    const int scol = ((lane & 7) ^ srow) * 8;

#define STAGEB(tt, half)                                                                           \
    { const int k0_ = (tt) * 64;                                                                   \
      _Pragma("unroll")                                                                            \
      for (int i_ = 0; i_ < CWB; ++i_) {                                                           \
        const int c_ = i_ * 4 + wave;                                                              \
        __builtin_amdgcn_global_load_lds(                                                          \
          (const __attribute__((address_space(1))) void*)(Bt + (size_t)(n0 + c_ * 8 + srow) * 768 + k0_ + scol), \
          (__attribute__((address_space(3))) void*)(sB + (half) * (BN * 64) + c_ * 512), 16, 0, 0); } }

    STAGEB(0, 0);
    STAGEB(1, 1);

    if constexpr (F32IN) {
        const f32x4* w4 = (const f32x4*)lnw;
        const f32x4* b4 = (const f32x4*)lnb;
        f32x4 wv0 = w4[lane], wv1 = w4[64 + lane], wv2 = w4[128 + lane];
        f32x4 bv0 = b4[lane], bv1 = b4[64 + lane], bv2 = b4[128 + lane];
        for (int rr = 0; rr < RPW; ++rr) {
            const int r = wave * RPW + rr;
            const f32x4* xr = (const f32x4*)((const float*)xv + (size_t)(m0 + r) * 768);
            f32x4 f0 = xr[lane], f1 = xr[64 + lane], f2 = xr[128 + lane];
            float s = 0.f, ss = 0.f;
            #pragma unroll
            for (int k = 0; k < 4; ++k) {
                s += f0[k] + f1[k] + f2[k];
                ss += f0[k] * f0[k] + f1[k] * f1[k] + f2[k] * f2[k];
            }
            #pragma unroll
            for (int o = 32; o > 0; o >>= 1) { s += __shfl_down(s, o); ss += __shfl_down(ss, o); }
            s = __shfl(s, 0); ss = __shfl(ss, 0);
            const float mn = s * (1.f / 768);
            const float rs = rsqrtf(ss * (1.f / 768) - mn * mn + 1e-6f);
            const int rx7 = r & 7;
            const int slot = (lane >> 1) & 7;
            const int off = (lane & 1) * 4;
            #pragma unroll
            for (int j = 0; j < 3; ++j) {
                f32x4 fj = (j == 0) ? f0 : (j == 1) ? f1 : f2;
                f32x4 wj = (j == 0) ? wv0 : (j == 1) ? wv1 : wv2;
                f32x4 bj = (j == 0) ? bv0 : (j == 1) ? bv1 : bv2;
                bf16 t4[4];
                #pragma unroll
                for (int k = 0; k < 4; ++k)
                    t4[k] = __float2bfloat16((fj[k] - mn) * rs * wj[k] + bj[k]);
                const int kt = j * 4 + (lane >> 4);
                *(bf16x4*)&sA[r * 768 + kt * 64 + ((slot ^ rx7) << 3) + off] = *(bf16x4*)t4;
            }
        }
    } else {
        const f32x4* w4 = (const f32x4*)lnw;
        const f32x4* b4 = (const f32x4*)lnb;
        f32x4 w80 = w4[lane * 2], w81 = w4[lane * 2 + 1], w44 = w4[128 + lane];
        f32x4 b80 = b4[lane * 2], b81 = b4[lane * 2 + 1], b44 = b4[128 + lane];
        for (int rr = 0; rr < RPW; ++rr) {
            const int r = wave * RPW + rr;
            const bf16* xr = (const bf16*)xv + (size_t)(m0 + r) * 768;
            bf16x8 v8 = *(const bf16x8*)(xr + lane * 8);
            bf16x4 v4 = *(const bf16x4*)(xr + 512 + lane * 4);
            float f[12];
            #pragma unroll
            for (int k = 0; k < 8; ++k) f[k] = bf2f(v8[k]);
            #pragma unroll
            for (int k = 0; k < 4; ++k) f[8 + k] = bf2f(v4[k]);
            float s = 0.f, ss = 0.f;
            #pragma unroll
            for (int k = 0; k < 12; ++k) { s += f[k]; ss += f[k] * f[k]; }
            #pragma unroll
            for (int o = 32; o > 0; o >>= 1) { s += __shfl_down(s, o); ss += __shfl_down(ss, o); }
            s = __shfl(s, 0); ss = __shfl(ss, 0);
            const float mn = s * (1.f / 768);
            const float rs = rsqrtf(ss * (1.f / 768) - mn * mn + 1e-6f);
            const int rx7 = r & 7;
            bf16 t8[8];
            #pragma unroll
            for (int k = 0; k < 4; ++k) t8[k] = __float2bfloat16((f[k] - mn) * rs * w80[k] + b80[k]);
            #pragma unroll
            for (int k = 0; k < 4; ++k) t8[4 + k] = __float2bfloat16((f[4 + k] - mn) * rs * w81[k] + b81[k]);
            *(bf16x8*)&sA[r * 768 + (lane >> 3) * 64 + (((lane & 7) ^ rx7) << 3)] = *(bf16x8*)t8;
            bf16 t4[4];
            #pragma unroll
            for (int k = 0; k < 4; ++k) t4[k] = __float2bfloat16((f[8 + k] - mn) * rs * w44[k] + b44[k]);
            *(bf16x4*)&sA[r * 768 + (8 + (lane >> 4)) * 64 + ((((lane >> 1) & 7) ^ rx7) << 3) + (lane & 1) * 4]
                = *(bf16x4*)t4;
        }
    }
    asm volatile("s_waitcnt lgkmcnt(0)" ::: "memory");

    f32x4 acc[FM][FN] = {};
    #pragma unroll
    for (int t = 0; t < 12; ++t) {
        const int half = t & 1;
        if (t + 1 < 12) wait_vmcnt<CWB>();
        else            wait_vmcnt<0>();
        __builtin_amdgcn_s_barrier();
        const bf16* cB = sB + half * (BN * 64);
        #pragma unroll
        for (int kki = 0; kki < 2; ++kki) {
            const int kslot = kki * 4 + (lane >> 4);
            bf16x8 aF[FM], bF[FN];
            #pragma unroll
            for (int i = 0; i < FM; ++i) {
                const int row = wm + i * 16 + (lane & 15);
                aF[i] = *(const bf16x8*)(&sA[row * 768 + t * 64 + ((kslot ^ (row & 7)) * 8)]);
            }
            #pragma unroll
            for (int j = 0; j < FN; ++j) {
                const int row = wn + j * 16 + (lane & 15);
                bF[j] = *(const bf16x8*)(&cB[row * 64 + ((kslot ^ (row & 7)) * 8)]);
            }
            #pragma unroll
            for (int i = 0; i < FM; ++i) {
                #pragma unroll
                for (int j = 0; j < FN; ++j)
                    acc[i][j] = __builtin_amdgcn_mfma_f32_16x16x32_bf16(aF[i], bF[j], acc[i][j], 0, 0, 0);
            }
        }
        asm volatile("s_waitcnt lgkmcnt(0)" ::: "memory");
        __builtin_amdgcn_s_barrier();
        if (t + 2 < 12) STAGEB(t + 2, half);
    }
#undef STAGEB

    #pragma unroll
    for (int j = 0; j < FN; ++j) {
        const int colL = wn + j * 16 + (lane & 15);
        const float bj = bias[n0 + colL];
        #pragma unroll
        for (int i = 0; i < FM; ++i) {
            #pragma unroll
            for (int r = 0; r < 4; ++r) {
                const int rowL = wm + i * 16 + ((lane >> 4) << 2) + r;
                const int addr = rowL * BN + ((((colL >> 2) ^ (rowL & 7)) << 2) | (colL & 3));
                epi[addr] = acc[i][j][r] + bj;
            }
        }
    }
    __syncthreads();

    if constexpr (EPI == 1) {
        if (tid < BM * NHEADS) {
            const int rowL = tid & (BM - 1);
            const int h = tid / BM;
            auto erd = [&](int col) -> float {
                return epi[rowL * BN + ((((col >> 2) ^ (rowL & 7)) << 2) | (col & 3))];
            };
            float l0 = erd(48 + h * 4 + 0), l1 = erd(48 + h * 4 + 1);
            float l2 = erd(48 + h * 4 + 2), l3 = erd(48 + h * 4 + 3);
            float mx = fmaxf(fmaxf(l0, l1), fmaxf(l2, l3));
            float e0 = expf(l0 - mx), e1 = expf(l1 - mx), e2 = expf(l2 - mx), e3 = expf(l3 - mx);
            float inv = 1.f / (e0 + e1 + e2 + e3);
            float ee[4] = {e0, e1, e2, e3};
            const float rx = refp[(size_t)(m0 + rowL) * 2];
            const float ry = refp[(size_t)(m0 + rowL) * 2 + 1];
            float4* pp = (float4*)outv + ((size_t)(m0 + rowL) * NHEADS + h) * 4;
            #pragma unroll
            for (int p = 0; p < 4; ++p) {
                float ox = erd(h * 8 + p * 2), oy = erd(h * 8 + p * 2 + 1);
                pp[p] = make_float4(rx + ox * (1.f / WLVL), ry + oy * (1.f / HLVL), ee[p] * inv, 0.f);
            }
        }
    } else {
        constexpr int GPR8 = BN / 8;
        constexpr int GPT8 = (BM * BN / 8) / 256;
        #pragma unroll
        for (int k = 0; k < GPT8; ++k) {
            const int f = k * 256 + tid;
            const int rr = f / GPR8, cc = (f % GPR8) * 8;
            const int g0 = ((cc >> 2) ^ (rr & 7)) << 2;
            const int g1 = (((cc >> 2) + 1) ^ (rr & 7)) << 2;
            float4 v0 = *(const float4*)&epi[rr * BN + g0];
            float4 v1 = *(const float4*)&epi[rr * BN + g1];
            bf16 tmp[8];
            tmp[0] = __float2bfloat16(v0.x); tmp[1] = __float2bfloat16(v0.y);
            tmp[2] = __float2bfloat16(v0.z); tmp[3] = __float2bfloat16(v0.w);
            tmp[4] = __float2bfloat16(v1.x); tmp[5] = __float2bfloat16(v1.y);
            tmp[6] = __float2bfloat16(v1.z); tmp[7] = __float2bfloat16(v1.w);
            *(bf16x8*)((bf16*)outv + (size_t)(m0 + rr) * N + n0 + cc) = *(bf16x8*)tmp;
        }
    }
}

// ---------------- bilinear sample: branchless, image->XCD pinned, HEAD-MAJOR, head-major value ----
__global__ __launch_bounds__(256)
void sampler_kernel(const bf16* __restrict__ value, const float4* __restrict__ params,
                    bf16* __restrict__ attn_in)
{
    const int tid = threadIdx.x;
    const int b = blockIdx.x & 7;                   // image == XCD
    const int local = blockIdx.x >> 3;              // [0, 1152)
    const int h = local / 192;                      // head-major
    const int qc = local - h * 192;                 // q-chunk (16 q each)
    const int bl = b * LQ + qc * 16 + (tid >> 4);   // global query index
    const int g = bl * NHEADS + h;                  // query-head index
    const int lane16 = tid & 15;
    // value layout: (b, head, pix, 128) -- contiguous 1MB per (b,h)
    const bf16* vh = value + (((size_t)b * NHEADS + h) * LIN) * DHEAD + lane16 * 8;

    int offs[16];
    float wgt[16];
    #pragma unroll
    for (int p = 0; p < NPTS; ++p) {
        float4 pr = params[(size_t)g * 4 + p];
        float x = pr.x * (float)WLVL - 0.5f;
        float y = pr.y * (float)HLVL - 0.5f;
        float x0f = floorf(x), y0f = floorf(y);
        float wx1 = x - x0f, wy1 = y - y0f;
        float wx0 = 1.f - wx1, wy0 = 1.f - wy1;
        int x0 = (int)x0f, y0 = (int)y0f;
        #pragma unroll
        for (int dy = 0; dy < 2; ++dy) {
            const int yi = y0 + dy;
            const int yc = min(max(yi, 0), HLVL - 1);
            const float wy = (dy ? wy1 : wy0) * ((yi >= 0 && yi < HLVL) ? pr.z : 0.f);
            #pragma unroll
            for (int dx = 0; dx < 2; ++dx) {
                const int xi = x0 + dx;
                const int xc = min(max(xi, 0), WLVL - 1);
                const int idx = p * 4 + dy * 2 + dx;
                offs[idx] = (yc * WLVL + xc) * DHEAD;
                wgt[idx] = wy * (dx ? wx1 : wx0) * ((xi >= 0 && xi < WLVL) ? 1.f : 0.f);
            }
        }
    }
    bf16x8 v[16];
    #pragma unroll
    for (int i = 0; i < 16; ++i) v[i] = *(const bf16x8*)(vh + offs[i]);
    float acc[8] = {};
    #pragma unroll
    for (int i = 0; i < 16; ++i) {
        #pragma unroll
        for (int j = 0; j < 8; ++j)
            acc[j] += wgt[i] * bf2f(v[i][j]);
    }
    bf16 tmp[8];
    #pragma unroll
    for (int j = 0; j < 8; ++j) tmp[j] = __float2bfloat16(acc[j]);
    *(bf16x8*)(attn_in + (size_t)bl * CC + h * DHEAD + lane16 * 8) = *(bf16x8*)tmp;
}

// ---------------- depthwise 3x3 conv + bias + exact GELU (bf16 in/out, 4ch/thread) ----------------
__global__ __launch_bounds__(192)
void dwconv_gelu_kernel(const bf16* __restrict__ z, const float* __restrict__ dw_w,
                        const float* __restrict__ dw_b, bf16* __restrict__ g)
{
    const int tp = threadIdx.x / 48;
    const int tc = threadIdx.x % 48;
    const int m = blockIdx.x * 4 + tp;
    const int c = tc * 4;
    const int pix = m & 1023;
    const int h = pix >> 5, w = pix & 31;
    float acc[4];
    #pragma unroll
    for (int j = 0; j < 4; ++j) acc[j] = dw_b[c + j];
    #pragma unroll
    for (int dy = -1; dy <= 1; ++dy) {
        int hh2 = h + dy;
        if (hh2 < 0 || hh2 >= 32) continue;
        #pragma unroll
        for (int dx = -1; dx <= 1; ++dx) {
            int ww2 = w + dx;
            if (ww2 < 0 || ww2 >= 32) continue;
            bf16x4 vv = *(const bf16x4*)&z[(size_t)(m + dy * 32 + dx) * HID + c];
            #pragma unroll
            for (int j = 0; j < 4; ++j)
                acc[j] += bf2f(vv[j]) * dw_w[(c + j) * 9 + (dy + 1) * 3 + (dx + 1)];
        }
    }
    bf16 tmp[4];
    #pragma unroll
    for (int j = 0; j < 4; ++j) {
        float ge = acc[j] * 0.5f * (1.f + erff(acc[j] * 0.70710678118f));
        tmp[j] = __float2bfloat16(ge);
    }
    *(bf16x4*)&g[(size_t)m * HID + c] = *(bf16x4*)tmp;
}

extern "C" void kernel_launch(void* const* d_in, const int* in_sizes, int n_in,
                              void* d_out, int out_size, void* d_ws, size_t ws_size,
                              hipStream_t stream)
{
    const float* query = (const float*)d_in[0];
    const float* refp  = (const float*)d_in[1];
    const float* feat  = (const float*)d_in[2];
    const float* qn_w = (const float*)d_in[7];
    const float* qn_b = (const float*)d_in[8];
    const float* fn_w = (const float*)d_in[9];
    const float* fn_b = (const float*)d_in[10];
    const float* so_w = (const float*)d_in[11];
    const float* so_b = (const float*)d_in[12];
    const float* aw_w = (const float*)d_in[13];
    const float* aw_b = (const float*)d_in[14];
    const float* vp_w = (const float*)d_in[15];
    const float* vp_b = (const float*)d_in[16];
    const float* op_w = (const float*)d_in[17];
    const float* op_b = (const float*)d_in[18];
    const float* ffn_w = (const float*)d_in[19];
    const float* ffn_b = (const float*)d_in[20];
    const float* fc1_w = (const float*)d_in[21];
    const float* fc1_b = (const float*)d_in[22];
    const float* dw_w = (const float*)d_in[23];
    const float* dw_b = (const float*)d_in[24];
    const float* fc2_w = (const float*)d_in[25];
    const float* fc2_b = (const float*)d_in[26];
    float* out = (float*)d_out;

    if (ws_size < (size_t)125829632) return;
    char* ws = (char*)d_ws;
    bf16* vp_wt   = (bf16*)(ws + 0);
    bf16* op_wt   = (bf16*)(ws + 1179648);
    bf16* fc1_wt  = (bf16*)(ws + 2359296);
    bf16* fc2_wt  = (bf16*)(ws + 2654208);
    bf16* dots_wt = (bf16*)(ws + 2949120);
    float* dots_b = (float*)(ws + 3145728);
    char* paramsR = ws + 3146240;
    char* dotsR   = ws + 12583424;
    char* regA = ws + 25166336;
    char* regB = ws + 75497984;
    float4* params = (float4*)paramsR;
    bf16* g        = (bf16*)paramsR;
    bf16* z        = (bf16*)dotsR;
    bf16* f_ln    = (bf16*)regA;
    bf16* attn_in = (bf16*)regA;
    bf16* value = (bf16*)regB;
    bf16* s_bf  = (bf16*)regB;

    // ---- prep (weights) + LN(feat), one launch ----
    prep_kernel<<<744 + FROWS / 4, 256, 0, stream>>>(
        vp_w, op_w, fc1_w, fc2_w, so_w, so_b, aw_w, aw_b, feat, fn_w, fn_b,
        vp_wt, op_wt, fc1_wt, fc2_wt, dots_wt, dots_b, f_ln);

    // ---- MSDeformAttn ----
    ln_gemm_kernel<32, 128, 16, 64, true, 1><<<dim3(1, BLTOT / 32), 256, 0, stream>>>(
        query, qn_w, qn_b, dots_wt, dots_b, refp, params, BLTOT, 128);
    gemm_value_kernel<<<dim3(6, FROWS / 128), 512, 0, stream>>>(
        f_ln, vp_wt, vp_b, value, FROWS, 768, 768);
    sampler_kernel<<<(BLTOT * NHEADS) / 16, 256, 0, stream>>>(value, params, attn_in);
    gemm_kernel<64, 128, 32, 64, 3><<<dim3(6, BLTOT / 64), 256, 0, stream>>>(
        attn_in, op_wt, op_b, query, s_bf, BLTOT, 768, 768);    // s_bf = query + attn (bf16)

    // ---- ConvFFN ----
    ln_gemm_kernel<32, 64, 32, 16, false, 0><<<dim3(3, BLTOT / 32), 256, 0, stream>>>(
        s_bf, ffn_w, ffn_b, fc1_wt, fc1_b, nullptr, z, BLTOT, HID);
    dwconv_gelu_kernel<<<BLTOT / 4, 192, 0, stream>>>(z, dw_w, dw_b, g);
    gemm_kernel<64, 128, 32, 64, 4><<<dim3(6, BLTOT / 64), 256, 0, stream>>>(
        g, fc2_wt, fc2_b, s_bf, out, BLTOT, 768, HID);          // out = s_bf + ffn (f32)
}

// Round 13
// 291.497 us; speedup vs baseline: 1.0825x; 1.0409x over previous
//
#include <hip/hip_runtime.h>
#include <hip/hip_bf16.h>
#include <math.h>

typedef __hip_bfloat16 bf16;
typedef short bf16x8 __attribute__((ext_vector_type(8)));
typedef short bf16x4 __attribute__((ext_vector_type(4)));
typedef float f32x4 __attribute__((ext_vector_type(4)));

#define NB 8
#define LQ 3072
#define CC 768
#define NHEADS 6
#define NPTS 4
#define DHEAD 128
#define HLVL 64
#define WLVL 64
#define LIN 4096
#define HID 192
#define BLTOT 24576   // NB*LQ
#define FROWS 32768   // NB*LIN

__device__ __forceinline__ float bf2f(short u)
{ return __uint_as_float(((unsigned)(unsigned short)u) << 16); }

template<int N_>
__device__ __forceinline__ void wait_vmcnt()
{
    if constexpr (N_ == 0)      asm volatile("s_waitcnt vmcnt(0)" ::: "memory");
    else if constexpr (N_ == 2) asm volatile("s_waitcnt vmcnt(2)" ::: "memory");
    else if constexpr (N_ == 4) asm volatile("s_waitcnt vmcnt(4)" ::: "memory");
    else if constexpr (N_ == 6) asm volatile("s_waitcnt vmcnt(6)" ::: "memory");
    else if constexpr (N_ == 8) asm volatile("s_waitcnt vmcnt(8)" ::: "memory");
    else static_assert(N_ == 0, "add a vmcnt case");
}

// ---------------- merged prep: 4 weight transposes + dots weight + LN(feat), one launch ----------
__device__ __forceinline__ void wt_tile(float (*t)[65], const float* __restrict__ src,
                                        bf16* __restrict__ dst, int K, int N, int tn0, int tk0)
{
    const int r = threadIdx.x >> 6, c = threadIdx.x & 63;
    #pragma unroll
    for (int i = 0; i < 16; ++i)
        t[i * 4 + r][c] = src[(size_t)(tk0 + i * 4 + r) * N + tn0 + c];
    __syncthreads();
    #pragma unroll
    for (int i = 0; i < 16; ++i)
        dst[(size_t)(tn0 + i * 4 + r) * K + tk0 + c] = __float2bfloat16(t[c][i * 4 + r]);
}

__global__ __launch_bounds__(256)
void prep_kernel(const float* __restrict__ vp_w, const float* __restrict__ op_w,
                 const float* __restrict__ fc1_w, const float* __restrict__ fc2_w,
                 const float* __restrict__ so_w, const float* __restrict__ so_b,
                 const float* __restrict__ aw_w, const float* __restrict__ aw_b,
                 const float* __restrict__ feat, const float* __restrict__ fn_w,
                 const float* __restrict__ fn_b,
                 bf16* __restrict__ vp_wt, bf16* __restrict__ op_wt,
                 bf16* __restrict__ fc1_wt, bf16* __restrict__ fc2_wt,
                 bf16* __restrict__ dots_wt, float* __restrict__ db,
                 bf16* __restrict__ f_ln)
{
    __shared__ float t[64][65];
    int b = blockIdx.x;
    if (b < 144)      wt_tile(t, vp_w, vp_wt, 768, 768, (b % 12) * 64, (b / 12) * 64);
    else if (b < 288) { b -= 144; wt_tile(t, op_w, op_wt, 768, 768, (b % 12) * 64, (b / 12) * 64); }
    else if (b < 324) { b -= 288; wt_tile(t, fc1_w, fc1_wt, 768, 192, (b % 3) * 64, (b / 3) * 64); }
    else if (b < 360) { b -= 324; wt_tile(t, fc2_w, fc2_wt, 192, 768, (b % 12) * 64, (b / 12) * 64); }
    else if (b < 744) {
        b -= 360;
        int i = b * 256 + threadIdx.x;          // over 128*768
        if (i < 128 * 768) {
            int n = i / 768, k = i - n * 768;
            float v = 0.f;
            if (n < 48) v = so_w[(size_t)k * 48 + n];
            else if (n < 72) v = aw_w[(size_t)k * 24 + (n - 48)];
            dots_wt[i] = __float2bfloat16(v);
        }
        if (i < 128) {
            float bv = 0.f;
            if (i < 48) bv = so_b[i];
            else if (i < 72) bv = aw_b[i - 48];
            db[i] = bv;
        }
    } else {
        // LN(feat) -> f_ln, wave per row
        const int row = (b - 744) * 4 + (threadIdx.x >> 6);
        const int lane = threadIdx.x & 63;
        const f32x4* xr = (const f32x4*)(feat + (size_t)row * CC);
        f32x4 f0 = xr[lane], f1 = xr[64 + lane], f2 = xr[128 + lane];
        float s = 0.f, ss = 0.f;
        #pragma unroll
        for (int k = 0; k < 4; ++k) {
            s += f0[k] + f1[k] + f2[k];
            ss += f0[k] * f0[k] + f1[k] * f1[k] + f2[k] * f2[k];
        }
        #pragma unroll
        for (int o = 32; o > 0; o >>= 1) { s += __shfl_down(s, o); ss += __shfl_down(ss, o); }
        s = __shfl(s, 0); ss = __shfl(ss, 0);
        const float m = s * (1.f / CC);
        const float rs = rsqrtf(ss * (1.f / CC) - m * m + 1e-6f);
        const f32x4* w4 = (const f32x4*)fn_w;
        const f32x4* b4 = (const f32x4*)fn_b;
        bf16* orow = f_ln + (size_t)row * CC;
        #pragma unroll
        for (int j = 0; j < 3; ++j) {
            f32x4 fj = (j == 0) ? f0 : (j == 1) ? f1 : f2;
            f32x4 wj = w4[j * 64 + lane], bj = b4[j * 64 + lane];
            bf16 t4[4];
            #pragma unroll
            for (int k = 0; k < 4; ++k) t4[k] = __float2bfloat16((fj[k] - m) * rs * wj[k] + bj[k]);
            *(bf16x4*)(orow + j * 256 + lane * 4) = *(bf16x4*)t4;
        }
    }
}

// ---------------- bf16 MFMA GEMM (256 thr): 2-deep pipelined, XOR-swizzled LDS ----------------
// MODE 0: bf16 out = acc+bias
// MODE 3: bf16 out = acc+bias+res_f32   (res prefetched to regs)
// MODE 4: f32  out = acc+bias+res_bf16  (res prefetched to regs)
template<int BM, int BN, int WM, int WN, int MODE>
__global__ __launch_bounds__(256)
void gemm_kernel(const bf16* __restrict__ A, const bf16* __restrict__ Bt,
                 const float* __restrict__ bias, const void* __restrict__ resv,
                 void* __restrict__ outv, int M, int N, int K)
{
    constexpr int WAVES_N = BN / WN;
    constexpr int FM = WM / 16, FN = WN / 16;
    constexpr int CWA = BM / 32;
    constexpr int CWB = BN / 32;
    constexpr int LPT = CWA + CWB;
    constexpr int ABYTES = BM * 256;
    constexpr int DBUF_BYTES = (BM + BN) * 256;
    constexpr int EPI_BYTES = BM * BN * 4;
    constexpr size_t SMEM_BYTES = DBUF_BYTES > EPI_BYTES ? DBUF_BYTES : EPI_BYTES;
    __shared__ __align__(16) char smem[SMEM_BYTES];
    bf16* sA = (bf16*)smem;
    bf16* sB = (bf16*)(smem + ABYTES);
    float* epi = (float*)smem;

    const int tid = threadIdx.x;
    const int lane = tid & 63;
    const int wave = tid >> 6;

    const int nwgx = gridDim.x;
    const int nwg = nwgx * gridDim.y;
    const int bid = blockIdx.y * nwgx + blockIdx.x;
    const int swz = (bid & 7) * (nwg >> 3) + (bid >> 3);
    const int m0 = (swz / nwgx) * BM;
    const int n0 = (swz % nwgx) * BN;

    const int wm = (wave / WAVES_N) * WM;
    const int wn = (wave % WAVES_N) * WN;

    const int srow = lane >> 3;
    const int scol = ((lane & 7) ^ srow) * 8;

    constexpr int GPR8 = BN / 8;
    constexpr int GPT8 = (BM * BN / 8) / 256;
    constexpr int QPR4 = BN / 4;
    constexpr int QPT4 = (BM * BN / 4) / 256;
    float4 pr0[GPT8], pr1[GPT8];
    bf16x4 prb[QPT4];
    if constexpr (MODE == 3) {
        const float* resf = (const float*)resv;
        #pragma unroll
        for (int k = 0; k < GPT8; ++k) {
            const int f = k * 256 + tid;
            const int rr = f / GPR8, cc = (f % GPR8) * 8;
            const size_t gidx = (size_t)(m0 + rr) * N + n0 + cc;
            pr0[k] = *(const float4*)&resf[gidx];
            pr1[k] = *(const float4*)&resf[gidx + 4];
        }
    }
    if constexpr (MODE == 4) {
        const bf16* resb = (const bf16*)resv;
        #pragma unroll
        for (int k = 0; k < QPT4; ++k) {
            const int f = k * 256 + tid;
            const int rr = f / QPR4, cc = (f % QPR4) * 4;
            prb[k] = *(const bf16x4*)&resb[(size_t)(m0 + rr) * N + n0 + cc];
        }
    }

#define STAGE(tt, half)                                                                            \
    { const int k0_ = (tt) * 64;                                                                   \
      _Pragma("unroll")                                                                            \
      for (int i_ = 0; i_ < CWA; ++i_) {                                                           \
        const int c_ = i_ * 4 + wave;                                                              \
        __builtin_amdgcn_global_load_lds(                                                          \
          (const __attribute__((address_space(1))) void*)(A + (size_t)(m0 + c_ * 8 + srow) * K + k0_ + scol), \
          (__attribute__((address_space(3))) void*)(sA + (half) * (BM * 64) + c_ * 512), 16, 0, 0); } \
      _Pragma("unroll")                                                                            \
      for (int i_ = 0; i_ < CWB; ++i_) {                                                           \
        const int c_ = i_ * 4 + wave;                                                              \
        __builtin_amdgcn_global_load_lds(                                                          \
          (const __attribute__((address_space(1))) void*)(Bt + (size_t)(n0 + c_ * 8 + srow) * K + k0_ + scol), \
          (__attribute__((address_space(3))) void*)(sB + (half) * (BN * 64) + c_ * 512), 16, 0, 0); } }

    f32x4 acc[FM][FN] = {};
    const int nt = K >> 6;

    STAGE(0, 0);
    STAGE(1, 1);

    for (int t = 0; t < nt; ++t) {
        const int half = t & 1;
        if (t + 1 < nt) wait_vmcnt<LPT>();
        else            wait_vmcnt<0>();
        __builtin_amdgcn_s_barrier();
        const bf16* cA = sA + half * (BM * 64);
        const bf16* cB = sB + half * (BN * 64);
        #pragma unroll
        for (int kki = 0; kki < 2; ++kki) {
            const int kslot = kki * 4 + (lane >> 4);
            bf16x8 aF[FM], bF[FN];
            #pragma unroll
            for (int i = 0; i < FM; ++i) {
                const int row = wm + i * 16 + (lane & 15);
                aF[i] = *(const bf16x8*)(&cA[row * 64 + ((kslot ^ (row & 7)) * 8)]);
            }
            #pragma unroll
            for (int j = 0; j < FN; ++j) {
                const int row = wn + j * 16 + (lane & 15);
                bF[j] = *(const bf16x8*)(&cB[row * 64 + ((kslot ^ (row & 7)) * 8)]);
            }
            #pragma unroll
            for (int i = 0; i < FM; ++i) {
                #pragma unroll
                for (int j = 0; j < FN; ++j)
                    acc[i][j] = __builtin_amdgcn_mfma_f32_16x16x32_bf16(aF[i], bF[j], acc[i][j], 0, 0, 0);
            }
        }
        asm volatile("s_waitcnt lgkmcnt(0)" ::: "memory");
        __builtin_amdgcn_s_barrier();
        if (t + 2 < nt) STAGE(t + 2, half);
    }
#undef STAGE

    #pragma unroll
    for (int j = 0; j < FN; ++j) {
        const int colL = wn + j * 16 + (lane & 15);
        const float bj = bias[n0 + colL];
        #pragma unroll
        for (int i = 0; i < FM; ++i) {
            #pragma unroll
            for (int r = 0; r < 4; ++r) {
                const int rowL = wm + i * 16 + ((lane >> 4) << 2) + r;
                const int addr = rowL * BN + ((((colL >> 2) ^ (rowL & 7)) << 2) | (colL & 3));
                epi[addr] = acc[i][j][r] + bj;
            }
        }
    }
    __syncthreads();

    if constexpr (MODE == 0 || MODE == 3) {
        #pragma unroll
        for (int k = 0; k < GPT8; ++k) {
            const int f = k * 256 + tid;
            const int rr = f / GPR8, cc = (f % GPR8) * 8;
            const int g0 = ((cc >> 2) ^ (rr & 7)) << 2;
            const int g1 = (((cc >> 2) + 1) ^ (rr & 7)) << 2;
            float4 v0 = *(const float4*)&epi[rr * BN + g0];
            float4 v1 = *(const float4*)&epi[rr * BN + g1];
            if constexpr (MODE == 3) {
                v0.x += pr0[k].x; v0.y += pr0[k].y; v0.z += pr0[k].z; v0.w += pr0[k].w;
                v1.x += pr1[k].x; v1.y += pr1[k].y; v1.z += pr1[k].z; v1.w += pr1[k].w;
            }
            bf16 tmp[8];
            tmp[0] = __float2bfloat16(v0.x); tmp[1] = __float2bfloat16(v0.y);
            tmp[2] = __float2bfloat16(v0.z); tmp[3] = __float2bfloat16(v0.w);
            tmp[4] = __float2bfloat16(v1.x); tmp[5] = __float2bfloat16(v1.y);
            tmp[6] = __float2bfloat16(v1.z); tmp[7] = __float2bfloat16(v1.w);
            *(bf16x8*)((bf16*)outv + (size_t)(m0 + rr) * N + n0 + cc) = *(bf16x8*)tmp;
        }
    } else {
        #pragma unroll
        for (int k = 0; k < QPT4; ++k) {
            const int f = k * 256 + tid;
            const int rr = f / QPR4, cc = (f % QPR4) * 4;
            const int gs = ((cc >> 2) ^ (rr & 7)) << 2;
            float4 v = *(const float4*)&epi[rr * BN + gs];
            if constexpr (MODE == 4) {
                v.x += bf2f(prb[k][0]); v.y += bf2f(prb[k][1]);
                v.z += bf2f(prb[k][2]); v.w += bf2f(prb[k][3]);
            }
            *(float4*)&((float*)outv)[(size_t)(m0 + rr) * N + n0 + cc] = v;
        }
    }
}

// ============== FUSED value-GEMM + dots-projection single launch (512 threads) ==============
// blocks [0,1536): value GEMM 128x128, head-major output
// blocks [1536,2304): LN(query)+dots GEMM (BM=32,BN=128)+loc-softmax -> params
#define VAL_BLOCKS 1536
#define DOTS_BLOCKS 768

__device__ void value_body(char* smem,
                           const bf16* __restrict__ A, const bf16* __restrict__ Bt,
                           const float* __restrict__ bias, bf16* __restrict__ outb)
{
    constexpr int BM = 128, BN = 128;
    constexpr int FM = 2, FN = 4;
    constexpr int LPT = 4;
    constexpr int K = 768;
    bf16* sA = (bf16*)smem;
    bf16* sB = (bf16*)(smem + 2 * BM * 128);
    float* epi = (float*)smem;

    const int tid = threadIdx.x;
    const int lane = tid & 63;
    const int wave = tid >> 6;

    const int bid = blockIdx.x;
    const int swz = (bid & 7) * (VAL_BLOCKS >> 3) + (bid >> 3);
    const int m0 = (swz / 6) * BM;
    const int n0 = (swz % 6) * BN;

    const int wm = (wave >> 1) * 32;
    const int wn = (wave & 1) * 64;
    const int srow = lane >> 3;
    const int scol = ((lane & 7) ^ srow) * 8;

#define STAGEV(tt, half)                                                                           \
    { const int k0_ = (tt) * 64;                                                                   \
      _Pragma("unroll")                                                                            \
      for (int i_ = 0; i_ < 2; ++i_) {                                                             \
        const int c_ = i_ * 8 + wave;                                                              \
        __builtin_amdgcn_global_load_lds(                                                          \
          (const __attribute__((address_space(1))) void*)(A + (size_t)(m0 + c_ * 8 + srow) * K + k0_ + scol), \
          (__attribute__((address_space(3))) void*)(sA + (half) * (BM * 64) + c_ * 512), 16, 0, 0); } \
      _Pragma("unroll")                                                                            \
      for (int i_ = 0; i_ < 2; ++i_) {                                                             \
        const int c_ = i_ * 8 + wave;                                                              \
        __builtin_amdgcn_global_load_lds(                                                          \
          (const __attribute__((address_space(1))) void*)(Bt + (size_t)(n0 + c_ * 8 + srow) * K + k0_ + scol), \
          (__attribute__((address_space(3))) void*)(sB + (half) * (BN * 64) + c_ * 512), 16, 0, 0); } }

    f32x4 acc[FM][FN] = {};
    STAGEV(0, 0);
    STAGEV(1, 1);

    for (int t = 0; t < 12; ++t) {
        const int half = t & 1;
        if (t + 1 < 12) wait_vmcnt<LPT>();
        else            wait_vmcnt<0>();
        __builtin_amdgcn_s_barrier();
        const bf16* cA = sA + half * (BM * 64);
        const bf16* cB = sB + half * (BN * 64);
        #pragma unroll
        for (int kki = 0; kki < 2; ++kki) {
            const int kslot = kki * 4 + (lane >> 4);
            bf16x8 aF[FM], bF[FN];
            #pragma unroll
            for (int i = 0; i < FM; ++i) {
                const int row = wm + i * 16 + (lane & 15);
                aF[i] = *(const bf16x8*)(&cA[row * 64 + ((kslot ^ (row & 7)) * 8)]);
            }
            #pragma unroll
            for (int j = 0; j < FN; ++j) {
                const int row = wn + j * 16 + (lane & 15);
                bF[j] = *(const bf16x8*)(&cB[row * 64 + ((kslot ^ (row & 7)) * 8)]);
            }
            #pragma unroll
            for (int i = 0; i < FM; ++i) {
                #pragma unroll
                for (int j = 0; j < FN; ++j)
                    acc[i][j] = __builtin_amdgcn_mfma_f32_16x16x32_bf16(aF[i], bF[j], acc[i][j], 0, 0, 0);
            }
        }
        asm volatile("s_waitcnt lgkmcnt(0)" ::: "memory");
        __builtin_amdgcn_s_barrier();
        if (t + 2 < 12) STAGEV(t + 2, half);
    }
#undef STAGEV

    #pragma unroll
    for (int j = 0; j < FN; ++j) {
        const int colL = wn + j * 16 + (lane & 15);
        const float bj = bias[n0 + colL];
        #pragma unroll
        for (int i = 0; i < FM; ++i) {
            #pragma unroll
            for (int r = 0; r < 4; ++r) {
                const int rowL = wm + i * 16 + ((lane >> 4) << 2) + r;
                const int addr = rowL * BN + ((((colL >> 2) ^ (rowL & 7)) << 2) | (colL & 3));
                epi[addr] = acc[i][j][r] + bj;
            }
        }
    }
    __syncthreads();
    // head-major store: out (b, head, pix, 128); n0 multiple of 128 -> one head per block
    const int hd = n0 >> 7;
    const int img = m0 >> 12;
    const int pix0 = m0 & 4095;
    bf16* obase = outb + (((size_t)img * NHEADS + hd) * LIN + pix0) * DHEAD;
    #pragma unroll
    for (int k = 0; k < 4; ++k) {
        const int f = k * 512 + tid;
        const int rr = f >> 4, cc = (f & 15) * 8;
        const int g0 = ((cc >> 2) ^ (rr & 7)) << 2;
        const int g1 = (((cc >> 2) + 1) ^ (rr & 7)) << 2;
        float4 v0 = *(const float4*)&epi[rr * BN + g0];
        float4 v1 = *(const float4*)&epi[rr * BN + g1];
        bf16 tmp[8];
        tmp[0] = __float2bfloat16(v0.x); tmp[1] = __float2bfloat16(v0.y);
        tmp[2] = __float2bfloat16(v0.z); tmp[3] = __float2bfloat16(v0.w);
        tmp[4] = __float2bfloat16(v1.x); tmp[5] = __float2bfloat16(v1.y);
        tmp[6] = __float2bfloat16(v1.z); tmp[7] = __float2bfloat16(v1.w);
        *(bf16x8*)(obase + (size_t)rr * DHEAD + cc) = *(bf16x8*)tmp;
    }
}

__device__ void dots_body(char* smem,
                          const float* __restrict__ query, const float* __restrict__ lnw,
                          const float* __restrict__ lnb, const bf16* __restrict__ Bt,
                          const float* __restrict__ bias, const float* __restrict__ refp,
                          float4* __restrict__ params)
{
    constexpr int BM = 32, BN = 128;
    constexpr int FM = 1, FN = 2;               // wave tile 16x32; 8 waves = 2x4
    bf16* sA = (bf16*)smem;                     // 32*768*2 = 48KB
    bf16* sB = (bf16*)(smem + BM * 768 * 2);    // 2*16KB = 32KB
    float* epi = (float*)sB;                    // 16KB (reuses sB)

    const int tid = threadIdx.x;
    const int lane = tid & 63;
    const int wave = tid >> 6;

    const int bid = blockIdx.x - VAL_BLOCKS;
    const int swz = (bid & 7) * (DOTS_BLOCKS >> 3) + (bid >> 3);
    const int m0 = swz * BM;

    const int wm = (wave >> 2) * 16;
    const int wn = (wave & 3) * 32;
    const int srow = lane >> 3;
    const int scol = ((lane & 7) ^ srow) * 8;

#define STAGED(tt, half)                                                                           \
    { const int k0_ = (tt) * 64;                                                                   \
      _Pragma("unroll")                                                                            \
      for (int i_ = 0; i_ < 2; ++i_) {                                                             \
        const int c_ = i_ * 8 + wave;                                                              \
        __builtin_amdgcn_global_load_lds(                                                          \
          (const __attribute__((address_space(1))) void*)(Bt + (size_t)(c_ * 8 + srow) * 768 + k0_ + scol), \
          (__attribute__((address_space(3))) void*)(sB + (half) * (BN * 64) + c_ * 512), 16, 0, 0); } }

    STAGED(0, 0);
    STAGED(1, 1);

    // LN phase: 8 waves x 4 rows into swizzled sA
    {
        const f32x4* w4 = (const f32x4*)lnw;
        const f32x4* b4 = (const f32x4*)lnb;
        f32x4 wv0 = w4[lane], wv1 = w4[64 + lane], wv2 = w4[128 + lane];
        f32x4 bv0 = b4[lane], bv1 = b4[64 + lane], bv2 = b4[128 + lane];
        #pragma unroll
        for (int rr = 0; rr < 4; ++rr) {
            const int r = wave * 4 + rr;
            const f32x4* xr = (const f32x4*)(query + (size_t)(m0 + r) * 768);
            f32x4 f0 = xr[lane], f1 = xr[64 + lane], f2 = xr[128 + lane];
            float s = 0.f, ss = 0.f;
            #pragma unroll
            for (int k = 0; k < 4; ++k) {
                s += f0[k] + f1[k] + f2[k];
                ss += f0[k] * f0[k] + f1[k] * f1[k] + f2[k] * f2[k];
            }
            #pragma unroll
            for (int o = 32; o > 0; o >>= 1) { s += __shfl_down(s, o); ss += __shfl_down(ss, o); }
            s = __shfl(s, 0); ss = __shfl(ss, 0);
            const float mn = s * (1.f / 768);
            const float rs = rsqrtf(ss * (1.f / 768) - mn * mn + 1e-6f);
            const int rx7 = r & 7;
            const int slot = (lane >> 1) & 7;
            const int off = (lane & 1) * 4;
            #pragma unroll
            for (int j = 0; j < 3; ++j) {
                f32x4 fj = (j == 0) ? f0 : (j == 1) ? f1 : f2;
                f32x4 wj = (j == 0) ? wv0 : (j == 1) ? wv1 : wv2;
                f32x4 bj = (j == 0) ? bv0 : (j == 1) ? bv1 : bv2;
                bf16 t4[4];
                #pragma unroll
                for (int k = 0; k < 4; ++k)
                    t4[k] = __float2bfloat16((fj[k] - mn) * rs * wj[k] + bj[k]);
                const int kt = j * 4 + (lane >> 4);
                *(bf16x4*)&sA[r * 768 + kt * 64 + ((slot ^ rx7) << 3) + off] = *(bf16x4*)t4;
            }
        }
    }
    asm volatile("s_waitcnt lgkmcnt(0)" ::: "memory");

    f32x4 acc[FM][FN] = {};
    #pragma unroll
    for (int t = 0; t < 12; ++t) {
        const int half = t & 1;
        if (t + 1 < 12) wait_vmcnt<2>();
        else            wait_vmcnt<0>();
        __builtin_amdgcn_s_barrier();
        const bf16* cB = sB + half * (BN * 64);
        #pragma unroll
        for (int kki = 0; kki < 2; ++kki) {
            const int kslot = kki * 4 + (lane >> 4);
            bf16x8 aF[FM], bF[FN];
            #pragma unroll
            for (int i = 0; i < FM; ++i) {
                const int row = wm + i * 16 + (lane & 15);
                aF[i] = *(const bf16x8*)(&sA[row * 768 + t * 64 + ((kslot ^ (row & 7)) * 8)]);
            }
            #pragma unroll
            for (int j = 0; j < FN; ++j) {
                const int row = wn + j * 16 + (lane & 15);
                bF[j] = *(const bf16x8*)(&cB[row * 64 + ((kslot ^ (row & 7)) * 8)]);
            }
            #pragma unroll
            for (int i = 0; i < FM; ++i) {
                #pragma unroll
                for (int j = 0; j < FN; ++j)
                    acc[i][j] = __builtin_amdgcn_mfma_f32_16x16x32_bf16(aF[i], bF[j], acc[i][j], 0, 0, 0);
            }
        }
        asm volatile("s_waitcnt lgkmcnt(0)" ::: "memory");
        __builtin_amdgcn_s_barrier();
        if (t + 2 < 12) STAGED(t + 2, half);
    }
#undef STAGED

    #pragma unroll
    for (int j = 0; j < FN; ++j) {
        const int colL = wn + j * 16 + (lane & 15);
        const float bj = bias[colL];
        #pragma unroll
        for (int r = 0; r < 4; ++r) {
            const int rowL = wm + ((lane >> 4) << 2) + r;
            const int addr = rowL * BN + ((((colL >> 2) ^ (rowL & 7)) << 2) | (colL & 3));
            epi[addr] = acc[0][j][r] + bj;
        }
    }
    __syncthreads();

    if (tid < BM * NHEADS) {
        const int rowL = tid & (BM - 1);
        const int h = tid / BM;
        auto erd = [&](int col) -> float {
            return epi[rowL * BN + ((((col >> 2) ^ (rowL & 7)) << 2) | (col & 3))];
        };
        float l0 = erd(48 + h * 4 + 0), l1 = erd(48 + h * 4 + 1);
        float l2 = erd(48 + h * 4 + 2), l3 = erd(48 + h * 4 + 3);
        float mx = fmaxf(fmaxf(l0, l1), fmaxf(l2, l3));
        float e0 = expf(l0 - mx), e1 = expf(l1 - mx), e2 = expf(l2 - mx), e3 = expf(l3 - mx);
        float inv = 1.f / (e0 + e1 + e2 + e3);
        float ee[4] = {e0, e1, e2, e3};
        const float rx = refp[(size_t)(m0 + rowL) * 2];
        const float ry = refp[(size_t)(m0 + rowL) * 2 + 1];
        float4* pp = params + ((size_t)(m0 + rowL) * NHEADS + h) * 4;
        #pragma unroll
        for (int p = 0; p < 4; ++p) {
            float ox = erd(h * 8 + p * 2), oy = erd(h * 8 + p * 2 + 1);
            pp[p] = make_float4(rx + ox * (1.f / WLVL), ry + oy * (1.f / HLVL), ee[p] * inv, 0.f);
        }
    }
}

__global__ __launch_bounds__(512)
void fused_value_dots_kernel(const bf16* __restrict__ f_ln, const bf16* __restrict__ vp_wt,
                             const float* __restrict__ vp_b, bf16* __restrict__ value,
                             const float* __restrict__ query, const float* __restrict__ qn_w,
                             const float* __restrict__ qn_b, const bf16* __restrict__ dots_wt,
                             const float* __restrict__ dots_b, const float* __restrict__ refp,
                             float4* __restrict__ params)
{
    __shared__ __align__(16) char smem[81920];   // max(64KB value, 80KB dots)
    if (blockIdx.x < VAL_BLOCKS)
        value_body(smem, f_ln, vp_wt, vp_b, value);
    else
        dots_body(smem, query, qn_w, qn_b, dots_wt, dots_b, refp, params);
}

// ---------------- FUSED LayerNorm + GEMM (K=768, bf16 in, A resident in LDS, B 2-deep) ----------
template<int BM, int BN, int WM, int WN>
__global__ __launch_bounds__(256)
void ln_gemm_kernel(const bf16* __restrict__ xv, const float* __restrict__ lnw,
                    const float* __restrict__ lnb, const bf16* __restrict__ Bt,
                    const float* __restrict__ bias, bf16* __restrict__ outv, int M, int N)
{
    constexpr int WAVES_N = BN / WN;
    constexpr int FM = WM / 16, FN = WN / 16;
    constexpr int CWB = BN / 32;
    constexpr int RPW = BM / 4;
    static_assert(BM * BN * 4 <= 2 * BN * 64 * 2, "epi must fit in sB");
    __shared__ __align__(16) bf16 sA[BM * 768];
    __shared__ __align__(16) char sBmem[2 * BN * 64 * 2];
    bf16* sB = (bf16*)sBmem;
    float* epi = (float*)sBmem;

    const int tid = threadIdx.x;
    const int lane = tid & 63;
    const int wave = tid >> 6;

    const int nwgx = gridDim.x;
    const int nwg = nwgx * gridDim.y;
    const int bid = blockIdx.y * nwgx + blockIdx.x;
    const int swz = (bid & 7) * (nwg >> 3) + (bid >> 3);
    const int m0 = (swz / nwgx) * BM;
    const int n0 = (swz % nwgx) * BN;

    const int wm = (wave / WAVES_N) * WM;
    const int wn = (wave % WAVES_N) * WN;
    const int srow = lane >> 3;
    const int scol = ((lane & 7) ^ srow) * 8;

#define STAGEB(tt, half)                                                                           \
    { const int k0_ = (tt) * 64;                                                                   \
      _Pragma("unroll")                                                                            \
      for (int i_ = 0; i_ < CWB; ++i_) {                                                           \
        const int c_ = i_ * 4 + wave;                                                              \
        __builtin_amdgcn_global_load_lds(                                                          \
          (const __attribute__((address_space(1))) void*)(Bt + (size_t)(n0 + c_ * 8 + srow) * 768 + k0_ + scol), \
          (__attribute__((address_space(3))) void*)(sB + (half) * (BN * 64) + c_ * 512), 16, 0, 0); } }

    STAGEB(0, 0);
    STAGEB(1, 1);

    {
        const f32x4* w4 = (const f32x4*)lnw;
        const f32x4* b4 = (const f32x4*)lnb;
        f32x4 w80 = w4[lane * 2], w81 = w4[lane * 2 + 1], w44 = w4[128 + lane];
        f32x4 b80 = b4[lane * 2], b81 = b4[lane * 2 + 1], b44 = b4[128 + lane];
        for (int rr = 0; rr < RPW; ++rr) {
            const int r = wave * RPW + rr;
            const bf16* xr = xv + (size_t)(m0 + r) * 768;
            bf16x8 v8 = *(const bf16x8*)(xr + lane * 8);
            bf16x4 v4 = *(const bf16x4*)(xr + 512 + lane * 4);
            float f[12];
            #pragma unroll
            for (int k = 0; k < 8; ++k) f[k] = bf2f(v8[k]);
            #pragma unroll
            for (int k = 0; k < 4; ++k) f[8 + k] = bf2f(v4[k]);
            float s = 0.f, ss = 0.f;
            #pragma unroll
            for (int k = 0; k < 12; ++k) { s += f[k]; ss += f[k] * f[k]; }
            #pragma unroll
            for (int o = 32; o > 0; o >>= 1) { s += __shfl_down(s, o); ss += __shfl_down(ss, o); }
            s = __shfl(s, 0); ss = __shfl(ss, 0);
            const float mn = s * (1.f / 768);
            const float rs = rsqrtf(ss * (1.f / 768) - mn * mn + 1e-6f);
            const int rx7 = r & 7;
            bf16 t8[8];
            #pragma unroll
            for (int k = 0; k < 4; ++k) t8[k] = __float2bfloat16((f[k] - mn) * rs * w80[k] + b80[k]);
            #pragma unroll
            for (int k = 0; k < 4; ++k) t8[4 + k] = __float2bfloat16((f[4 + k] - mn) * rs * w81[k] + b81[k]);
            *(bf16x8*)&sA[r * 768 + (lane >> 3) * 64 + (((lane & 7) ^ rx7) << 3)] = *(bf16x8*)t8;
            bf16 t4[4];
            #pragma unroll
            for (int k = 0; k < 4; ++k) t4[k] = __float2bfloat16((f[8 + k] - mn) * rs * w44[k] + b44[k]);
            *(bf16x4*)&sA[r * 768 + (8 + (lane >> 4)) * 64 + ((((lane >> 1) & 7) ^ rx7) << 3) + (lane & 1) * 4]
                = *(bf16x4*)t4;
        }
    }
    asm volatile("s_waitcnt lgkmcnt(0)" ::: "memory");

    f32x4 acc[FM][FN] = {};
    #pragma unroll
    for (int t = 0; t < 12; ++t) {
        const int half = t & 1;
        if (t + 1 < 12) wait_vmcnt<CWB>();
        else            wait_vmcnt<0>();
        __builtin_amdgcn_s_barrier();
        const bf16* cB = sB + half * (BN * 64);
        #pragma unroll
        for (int kki = 0; kki < 2; ++kki) {
            const int kslot = kki * 4 + (lane >> 4);
            bf16x8 aF[FM], bF[FN];
            #pragma unroll
            for (int i = 0; i < FM; ++i) {
                const int row = wm + i * 16 + (lane & 15);
                aF[i] = *(const bf16x8*)(&sA[row * 768 + t * 64 + ((kslot ^ (row & 7)) * 8)]);
            }
            #pragma unroll
            for (int j = 0; j < FN; ++j) {
                const int row = wn + j * 16 + (lane & 15);
                bF[j] = *(const bf16x8*)(&cB[row * 64 + ((kslot ^ (row & 7)) * 8)]);
            }
            #pragma unroll
            for (int i = 0; i < FM; ++i) {
                #pragma unroll
                for (int j = 0; j < FN; ++j)
                    acc[i][j] = __builtin_amdgcn_mfma_f32_16x16x32_bf16(aF[i], bF[j], acc[i][j], 0, 0, 0);
            }
        }
        asm volatile("s_waitcnt lgkmcnt(0)" ::: "memory");
        __builtin_amdgcn_s_barrier();
        if (t + 2 < 12) STAGEB(t + 2, half);
    }
#undef STAGEB

    #pragma unroll
    for (int j = 0; j < FN; ++j) {
        const int colL = wn + j * 16 + (lane & 15);
        const float bj = bias[n0 + colL];
        #pragma unroll
        for (int i = 0; i < FM; ++i) {
            #pragma unroll
            for (int r = 0; r < 4; ++r) {
                const int rowL = wm + i * 16 + ((lane >> 4) << 2) + r;
                const int addr = rowL * BN + ((((colL >> 2) ^ (rowL & 7)) << 2) | (colL & 3));
                epi[addr] = acc[i][j][r] + bj;
            }
        }
    }
    __syncthreads();

    constexpr int GPR8 = BN / 8;
    constexpr int GPT8 = (BM * BN / 8) / 256;
    #pragma unroll
    for (int k = 0; k < GPT8; ++k) {
        const int f = k * 256 + tid;
        const int rr = f / GPR8, cc = (f % GPR8) * 8;
        const int g0 = ((cc >> 2) ^ (rr & 7)) << 2;
        const int g1 = (((cc >> 2) + 1) ^ (rr & 7)) << 2;
        float4 v0 = *(const float4*)&epi[rr * BN + g0];
        float4 v1 = *(const float4*)&epi[rr * BN + g1];
        bf16 tmp[8];
        tmp[0] = __float2bfloat16(v0.x); tmp[1] = __float2bfloat16(v0.y);
        tmp[2] = __float2bfloat16(v0.z); tmp[3] = __float2bfloat16(v0.w);
        tmp[4] = __float2bfloat16(v1.x); tmp[5] = __float2bfloat16(v1.y);
        tmp[6] = __float2bfloat16(v1.z); tmp[7] = __float2bfloat16(v1.w);
        *(bf16x8*)(outv + (size_t)(m0 + rr) * N + n0 + cc) = *(bf16x8*)tmp;
    }
}

// ---------------- bilinear sample: branchless, image->XCD pinned, HEAD-MAJOR, head-major value ----
__global__ __launch_bounds__(256)
void sampler_kernel(const bf16* __restrict__ value, const float4* __restrict__ params,
                    bf16* __restrict__ attn_in)
{
    const int tid = threadIdx.x;
    const int b = blockIdx.x & 7;                   // image == XCD
    const int local = blockIdx.x >> 3;              // [0, 1152)
    const int h = local / 192;                      // head-major
    const int qc = local - h * 192;                 // q-chunk (16 q each)
    const int bl = b * LQ + qc * 16 + (tid >> 4);   // global query index
    const int g = bl * NHEADS + h;                  // query-head index
    const int lane16 = tid & 15;
    const bf16* vh = value + (((size_t)b * NHEADS + h) * LIN) * DHEAD + lane16 * 8;

    int offs[16];
    float wgt[16];
    #pragma unroll
    for (int p = 0; p < NPTS; ++p) {
        float4 pr = params[(size_t)g * 4 + p];
        float x = pr.x * (float)WLVL - 0.5f;
        float y = pr.y * (float)HLVL - 0.5f;
        float x0f = floorf(x), y0f = floorf(y);
        float wx1 = x - x0f, wy1 = y - y0f;
        float wx0 = 1.f - wx1, wy0 = 1.f - wy1;
        int x0 = (int)x0f, y0 = (int)y0f;
        #pragma unroll
        for (int dy = 0; dy < 2; ++dy) {
            const int yi = y0 + dy;
            const int yc = min(max(yi, 0), HLVL - 1);
            const float wy = (dy ? wy1 : wy0) * ((yi >= 0 && yi < HLVL) ? pr.z : 0.f);
            #pragma unroll
            for (int dx = 0; dx < 2; ++dx) {
                const int xi = x0 + dx;
                const int xc = min(max(xi, 0), WLVL - 1);
                const int idx = p * 4 + dy * 2 + dx;
                offs[idx] = (yc * WLVL + xc) * DHEAD;
                wgt[idx] = wy * (dx ? wx1 : wx0) * ((xi >= 0 && xi < WLVL) ? 1.f : 0.f);
            }
        }
    }
    bf16x8 v[16];
    #pragma unroll
    for (int i = 0; i < 16; ++i) v[i] = *(const bf16x8*)(vh + offs[i]);
    float acc[8] = {};
    #pragma unroll
    for (int i = 0; i < 16; ++i) {
        #pragma unroll
        for (int j = 0; j < 8; ++j)
            acc[j] += wgt[i] * bf2f(v[i][j]);
    }
    bf16 tmp[8];
    #pragma unroll
    for (int j = 0; j < 8; ++j) tmp[j] = __float2bfloat16(acc[j]);
    *(bf16x8*)(attn_in + (size_t)bl * CC + h * DHEAD + lane16 * 8) = *(bf16x8*)tmp;
}

// ---------------- depthwise 3x3 conv + bias + exact GELU (bf16 in/out, 4ch/thread) ----------------
__global__ __launch_bounds__(192)
void dwconv_gelu_kernel(const bf16* __restrict__ z, const float* __restrict__ dw_w,
                        const float* __restrict__ dw_b, bf16* __restrict__ g)
{
    const int tp = threadIdx.x / 48;
    const int tc = threadIdx.x % 48;
    const int m = blockIdx.x * 4 + tp;
    const int c = tc * 4;
    const int pix = m & 1023;
    const int h = pix >> 5, w = pix & 31;
    float acc[4];
    #pragma unroll
    for (int j = 0; j < 4; ++j) acc[j] = dw_b[c + j];
    #pragma unroll
    for (int dy = -1; dy <= 1; ++dy) {
        int hh2 = h + dy;
        if (hh2 < 0 || hh2 >= 32) continue;
        #pragma unroll
        for (int dx = -1; dx <= 1; ++dx) {
            int ww2 = w + dx;
            if (ww2 < 0 || ww2 >= 32) continue;
            bf16x4 vv = *(const bf16x4*)&z[(size_t)(m + dy * 32 + dx) * HID + c];
            #pragma unroll
            for (int j = 0; j < 4; ++j)
                acc[j] += bf2f(vv[j]) * dw_w[(c + j) * 9 + (dy + 1) * 3 + (dx + 1)];
        }
    }
    bf16 tmp[4];
    #pragma unroll
    for (int j = 0; j < 4; ++j) {
        float ge = acc[j] * 0.5f * (1.f + erff(acc[j] * 0.70710678118f));
        tmp[j] = __float2bfloat16(ge);
    }
    *(bf16x4*)&g[(size_t)m * HID + c] = *(bf16x4*)tmp;
}

extern "C" void kernel_launch(void* const* d_in, const int* in_sizes, int n_in,
                              void* d_out, int out_size, void* d_ws, size_t ws_size,
                              hipStream_t stream)
{
    const float* query = (const float*)d_in[0];
    const float* refp  = (const float*)d_in[1];
    const float* feat  = (const float*)d_in[2];
    const float* qn_w = (const float*)d_in[7];
    const float* qn_b = (const float*)d_in[8];
    const float* fn_w = (const float*)d_in[9];
    const float* fn_b = (const float*)d_in[10];
    const float* so_w = (const float*)d_in[11];
    const float* so_b = (const float*)d_in[12];
    const float* aw_w = (const float*)d_in[13];
    const float* aw_b = (const float*)d_in[14];
    const float* vp_w = (const float*)d_in[15];
    const float* vp_b = (const float*)d_in[16];
    const float* op_w = (const float*)d_in[17];
    const float* op_b = (const float*)d_in[18];
    const float* ffn_w = (const float*)d_in[19];
    const float* ffn_b = (const float*)d_in[20];
    const float* fc1_w = (const float*)d_in[21];
    const float* fc1_b = (const float*)d_in[22];
    const float* dw_w = (const float*)d_in[23];
    const float* dw_b = (const float*)d_in[24];
    const float* fc2_w = (const float*)d_in[25];
    const float* fc2_b = (const float*)d_in[26];
    float* out = (float*)d_out;

    if (ws_size < (size_t)125829632) return;
    char* ws = (char*)d_ws;
    bf16* vp_wt   = (bf16*)(ws + 0);
    bf16* op_wt   = (bf16*)(ws + 1179648);
    bf16* fc1_wt  = (bf16*)(ws + 2359296);
    bf16* fc2_wt  = (bf16*)(ws + 2654208);
    bf16* dots_wt = (bf16*)(ws + 2949120);
    float* dots_b = (float*)(ws + 3145728);
    char* paramsR = ws + 3146240;
    char* dotsR   = ws + 12583424;
    char* regA = ws + 25166336;
    char* regB = ws + 75497984;
    float4* params = (float4*)paramsR;
    bf16* g        = (bf16*)paramsR;
    bf16* z        = (bf16*)dotsR;
    bf16* f_ln    = (bf16*)regA;
    bf16* attn_in = (bf16*)regA;
    bf16* value = (bf16*)regB;
    bf16* s_bf  = (bf16*)regB;

    // ---- prep (weights) + LN(feat), one launch ----
    prep_kernel<<<744 + FROWS / 4, 256, 0, stream>>>(
        vp_w, op_w, fc1_w, fc2_w, so_w, so_b, aw_w, aw_b, feat, fn_w, fn_b,
        vp_wt, op_wt, fc1_wt, fc2_wt, dots_wt, dots_b, f_ln);

    // ---- MSDeformAttn: value GEMM + (LN(query)->dots->loc-softmax) fused in one launch ----
    fused_value_dots_kernel<<<VAL_BLOCKS + DOTS_BLOCKS, 512, 0, stream>>>(
        f_ln, vp_wt, vp_b, value, query, qn_w, qn_b, dots_wt, dots_b, refp, params);
    sampler_kernel<<<(BLTOT * NHEADS) / 16, 256, 0, stream>>>(value, params, attn_in);
    gemm_kernel<64, 128, 32, 64, 3><<<dim3(6, BLTOT / 64), 256, 0, stream>>>(
        attn_in, op_wt, op_b, query, s_bf, BLTOT, 768, 768);    // s_bf = query + attn (bf16)

    // ---- ConvFFN ----
    ln_gemm_kernel<32, 64, 32, 16><<<dim3(3, BLTOT / 32), 256, 0, stream>>>(
        s_bf, ffn_w, ffn_b, fc1_wt, fc1_b, z, BLTOT, HID);
    dwconv_gelu_kernel<<<BLTOT / 4, 192, 0, stream>>>(z, dw_w, dw_b, g);
    gemm_kernel<64, 128, 32, 64, 4><<<dim3(6, BLTOT / 64), 256, 0, stream>>>(
        g, fc2_wt, fc2_b, s_bf, out, BLTOT, 768, HID);          // out = s_bf + ffn (f32)
}